// Round 4
// baseline (163.016 us; speedup 1.0000x reference)
//
#include <hip/hip_runtime.h>

typedef unsigned short u16;
typedef unsigned int   u32;
typedef __attribute__((ext_vector_type(8))) __bf16 bf16x8;
typedef __attribute__((ext_vector_type(4))) float  f32x4;
typedef __attribute__((ext_vector_type(4))) u16    u16x4;
typedef __attribute__((ext_vector_type(4))) u32    u32x4;

#define DEV __device__ __forceinline__

DEV u16 f2b(float f){ union{float f;u32 u;}a; a.f=f; u32 r=a.u + 0x7FFFu + ((a.u>>16)&1u); return (u16)(r>>16); }
DEV float b2f(u16 h){ union{u32 u;float f;}a; a.u=((u32)h)<<16; return a.f; }

typedef __attribute__((address_space(1))) void* gp1;
typedef __attribute__((address_space(3))) void* lp3;
DEV void gl16(const void* g, void* l){
  __builtin_amdgcn_global_load_lds((gp1)g, (lp3)l, 16, 0, 0);
}

// ---------------------------------------------------------------------------
// prep (coalesced parts only): Ebf, Y0, Qt y-rows, Rt, invLam, P convert
// ---------------------------------------------------------------------------
__global__ __launch_bounds__(256) void k_prepc(
    const float* __restrict__ x,  const float* __restrict__ u,
    const float* __restrict__ C1, const float* __restrict__ D12,
    const float* __restrict__ Lam, const float* __restrict__ E,
    const float* __restrict__ C2, const float* __restrict__ D21,
    u16* Ebf, u16* Y0, u16* Qt, u16* Rt, float* invLam, u16* P)
{
  int idx = blockIdx.x * 256 + threadIdx.x;
  if (idx < 262144) {                       // Ebf, Y0 = 2I-E
    int i = idx >> 9, j = idx & 511;
    float e = E[idx];
    Ebf[idx] = f2b(e);
    float dij = (i == j) ? 2.f : 0.f;
    Y0[idx] = f2b(dij - e);
    return;
  }
  idx -= 262144;
  if (idx < 114688) {                       // Qt rows 512..639 (y part)
    int j = idx / 896, k = idx - j * 896;
    float v = (k < 512) ? C2[j * 512 + k]
              : (k < 768 ? D21[j * 256 + (k - 512)] : 0.f);
    Qt[(size_t)(512 + j) * 896 + k] = f2b(v);
    return;
  }
  idx -= 114688;
  if (idx < 229376) {                       // Rt (256x896): [C1 | 0 | D12]
    int n = idx / 896, k = idx - n * 896;
    float v = (k < 512) ? C1[n * 512 + k]
              : (k < 768 ? 0.f : D12[n * 128 + (k - 768)]);
    Rt[idx] = f2b(v);
    return;
  }
  idx -= 229376;
  if (idx < 256) { invLam[idx] = 1.f / Lam[idx * 256 + idx]; return; }
  idx -= 256;
  {                                         // P = [x | . | u] bf16
    int b = idx / 160, t = idx - b * 160;
    f32x4 s; u16* dst;
    if (t < 128) { s = *(const f32x4*)(x + (size_t)b * 512 + t * 4); dst = P + (size_t)b * 896 + t * 4; }
    else         { s = *(const f32x4*)(u + (size_t)b * 128 + (t - 128) * 4); dst = P + (size_t)b * 896 + 768 + (t - 128) * 4; }
    u16x4 o; o.x = f2b(s.x); o.y = f2b(s.y); o.z = f2b(s.z); o.w = f2b(s.w);
    *(u16x4*)dst = o;
  }
}

// ---------------------------------------------------------------------------
// tiled transposes: Z0 = 2I - E^T, McatT = [F;B1;B2]^T, D11Tb = (D11/lam)^T
// dst[a][b] = op(src[b][a]); 32x32 tiles, 256 thr (32x8)
// ---------------------------------------------------------------------------
__global__ __launch_bounds__(256) void k_transp(
    const float* __restrict__ E,  const float* __restrict__ F,
    const float* __restrict__ B1, const float* __restrict__ B2,
    const float* __restrict__ D11, const float* __restrict__ Lam,
    u16* Z0, u16* McatT, u16* D11Tb)
{
  __shared__ float t[32][33];
  int bid = blockIdx.x;
  const int tx = threadIdx.x & 31, ty = threadIdx.x >> 5;

  const float* src; u16* dst; int srcC, dstLD, nA, task;
  if (bid < 256)      { task = 0; src = E;   srcC = 512; dst = Z0;    dstLD = 512; nA = 16; }
  else if (bid < 512) { task = 1; src = F;   srcC = 512; dst = McatT; dstLD = 512; nA = 16; bid -= 256; }
  else if (bid < 640) { task = 2; src = B1;  srcC = 256; dst = McatT + (size_t)512 * 512; dstLD = 512; nA = 8;  bid -= 512; }
  else if (bid < 704) { task = 3; src = B2;  srcC = 128; dst = McatT + (size_t)768 * 512; dstLD = 512; nA = 4;  bid -= 640; }
  else                { task = 4; src = D11; srcC = 256; dst = D11Tb; dstLD = 256; nA = 8;  bid -= 704; }

  const int a0 = (bid % nA) * 32;     // dst-row block = src-col block
  const int b0 = (bid / nA) * 32;     // dst-col block = src-row block

  #pragma unroll
  for (int k = 0; k < 4; k++) {
    int srow = b0 + ty + 8 * k;
    float v = src[(size_t)srow * srcC + a0 + tx];
    if (task == 4) v *= 1.f / Lam[srow * 256 + srow];
    t[ty + 8 * k][tx] = v;
  }
  __syncthreads();
  #pragma unroll
  for (int k = 0; k < 4; k++) {
    int drow = a0 + ty + 8 * k, dcol = b0 + tx;
    float v = t[tx][ty + 8 * k];
    if (task == 0) v = ((drow == dcol) ? 2.f : 0.f) - v;
    dst[(size_t)drow * dstLD + dcol] = f2b(v);
  }
}

// ---------------------------------------------------------------------------
// NT bf16 MFMA GEMM, 128x128 tile, BK=32, 256 threads (2x2 waves, 64x64/wave)
// ---------------------------------------------------------------------------
struct GemmArgs {
  const u16* A; const u16* B; int K;
  float* outF;
  u16* outB; int ldB;
  u16* outBT;
  const u16* Yprev;
  const float* bv; const float* iLam;
  float* dxOut; float* yOut;
};

template<int EPI>
__global__ __launch_bounds__(256) void gemm_nt(GemmArgs g)
{
  __shared__ __align__(16) u16 As[128 * 32];
  __shared__ __align__(16) u16 Bs[128 * 32];
  const int tid = threadIdx.x;
  const int l = tid & 63, w = tid >> 6;
  const int bm = blockIdx.y, bn = blockIdx.x;
  const int K = g.K;
  const size_t rowb = (size_t)K * 2;
  const char* Ab = (const char*)g.A + (size_t)bm * 128 * rowb;
  const char* Bb = (const char*)g.B + (size_t)bn * 128 * rowb;
  const int o1 = w * 1024 + l * 16, o2 = o1 + 4096;
  const int r1 = o1 >> 6, r2 = o2 >> 6;
  const int c1 = (((o1 >> 4) ^ r1) & 3) << 4;
  const int c2 = (((o2 >> 4) ^ r2) & 3) << 4;
  char* AsB = (char*)As; char* BsB = (char*)Bs;
  const int wm = w >> 1, wn = w & 1;
  const int lr = l & 15, lk = l >> 4;
  const int slot = ((lk ^ lr) & 3) << 4;

  f32x4 acc[4][4];
  const f32x4 zz = {0.f, 0.f, 0.f, 0.f};
  #pragma unroll
  for (int i = 0; i < 4; i++)
    #pragma unroll
    for (int j = 0; j < 4; j++) acc[i][j] = zz;

  for (int k0 = 0; k0 < K; k0 += 32) {
    gl16(Ab + (size_t)r1 * rowb + k0 * 2 + c1, AsB + o1);
    gl16(Ab + (size_t)r2 * rowb + k0 * 2 + c2, AsB + o2);
    gl16(Bb + (size_t)r1 * rowb + k0 * 2 + c1, BsB + o1);
    gl16(Bb + (size_t)r2 * rowb + k0 * 2 + c2, BsB + o2);
    __syncthreads();
    bf16x8 af[4], bfv[4];
    #pragma unroll
    for (int mi = 0; mi < 4; mi++)
      af[mi] = *(const bf16x8*)(AsB + (wm * 64 + mi * 16 + lr) * 64 + slot);
    #pragma unroll
    for (int ni = 0; ni < 4; ni++)
      bfv[ni] = *(const bf16x8*)(BsB + (wn * 64 + ni * 16 + lr) * 64 + slot);
    #pragma unroll
    for (int mi = 0; mi < 4; mi++)
      #pragma unroll
      for (int ni = 0; ni < 4; ni++)
        acc[mi][ni] = __builtin_amdgcn_mfma_f32_16x16x32_bf16(af[mi], bfv[ni], acc[mi][ni], 0, 0, 0);
    __syncthreads();
  }

  #pragma unroll
  for (int mi = 0; mi < 4; mi++) {
    #pragma unroll
    for (int ni = 0; ni < 4; ni++) {
      const int row0 = bm * 128 + wm * 64 + mi * 16 + lk * 4;
      const int col  = bn * 128 + wn * 64 + ni * 16 + lr;
      if (EPI == 0) {
        const float bvc = g.bv[col], il = g.iLam[col];
        #pragma unroll
        for (int r = 0; r < 4; r++)
          g.outF[(size_t)(row0 + r) * 256 + col] = (acc[mi][ni][r] + bvc) * il;
      } else if (EPI == 1) {
        #pragma unroll
        for (int r = 0; r < 4; r++) {
          float v = acc[mi][ni][r];
          if (col < 512) g.dxOut[(size_t)(row0 + r) * 512 + col] = v;
          else           g.yOut[(size_t)(row0 + r) * 128 + (col - 512)] = v;
        }
      }
    }
  }
}

// ---------------------------------------------------------------------------
// NT bf16 MFMA GEMM, 64x64 tile for the small 512-wide chain
// ---------------------------------------------------------------------------
template<int EPI>
__global__ __launch_bounds__(256) void gemm64(GemmArgs g)
{
  __shared__ __align__(16) u16 As[64 * 32];
  __shared__ __align__(16) u16 Bs[64 * 32];
  const int tid = threadIdx.x;
  const int l = tid & 63, w = tid >> 6;
  const int bm = blockIdx.y, bn = blockIdx.x;
  const int K = g.K;
  const size_t rowb = (size_t)K * 2;
  const char* Ab = (const char*)g.A + (size_t)bm * 64 * rowb;
  const char* Bb = (const char*)g.B + (size_t)bn * 64 * rowb;
  const int o = tid * 16;
  const int r0 = o >> 6;
  const int cs = (((o >> 4) ^ r0) & 3) << 4;
  char* AsB = (char*)As; char* BsB = (char*)Bs;
  const int wm = w >> 1, wn = w & 1;
  const int lr = l & 15, lk = l >> 4;
  const int slot = ((lk ^ lr) & 3) << 4;

  f32x4 acc[2][2];
  const f32x4 zz = {0.f, 0.f, 0.f, 0.f};
  acc[0][0] = zz; acc[0][1] = zz; acc[1][0] = zz; acc[1][1] = zz;

  for (int k0 = 0; k0 < K; k0 += 32) {
    gl16(Ab + (size_t)r0 * rowb + k0 * 2 + cs, AsB + o);
    gl16(Bb + (size_t)r0 * rowb + k0 * 2 + cs, BsB + o);
    __syncthreads();
    bf16x8 af[2], bfv[2];
    #pragma unroll
    for (int mi = 0; mi < 2; mi++)
      af[mi] = *(const bf16x8*)(AsB + (wm * 32 + mi * 16 + lr) * 64 + slot);
    #pragma unroll
    for (int ni = 0; ni < 2; ni++)
      bfv[ni] = *(const bf16x8*)(BsB + (wn * 32 + ni * 16 + lr) * 64 + slot);
    #pragma unroll
    for (int mi = 0; mi < 2; mi++)
      #pragma unroll
      for (int ni = 0; ni < 2; ni++)
        acc[mi][ni] = __builtin_amdgcn_mfma_f32_16x16x32_bf16(af[mi], bfv[ni], acc[mi][ni], 0, 0, 0);
    __syncthreads();
  }

  #pragma unroll
  for (int mi = 0; mi < 2; mi++) {
    #pragma unroll
    for (int ni = 0; ni < 2; ni++) {
      const int row0 = bm * 64 + wm * 32 + mi * 16 + lk * 4;
      const int col  = bn * 64 + wn * 32 + ni * 16 + lr;
      if (EPI == 2) {
        #pragma unroll
        for (int r = 0; r < 4; r++)
          g.outB[(size_t)(row0 + r) * g.ldB + col] = f2b(acc[mi][ni][r]);
      } else if (EPI == 3) {
        #pragma unroll
        for (int r = 0; r < 4; r++)
          g.outBT[(size_t)col * 512 + (row0 + r)] = f2b(acc[mi][ni][r]);
      } else if (EPI == 4) {
        #pragma unroll
        for (int r = 0; r < 4; r++) {
          int row = row0 + r;
          float d = 2.f * b2f(g.Yprev[row * 512 + col]) - acc[mi][ni][r];
          g.outB[(size_t)row * 512 + col] = f2b(d);
        }
      }
    }
  }
}

// ---------------------------------------------------------------------------
// sequential tanh recurrence, blocked forward substitution.
// 512 blocks x 256 thr; 16 rows/block, 4 rows/wave, 16 lanes/row.
// lane c owns cols {8c..8c+7} u {128+8c..128+8c+7} (4 f32x4 acc).
// Per 16-col diag block: gather s to sBuf, redundant in-register 16-step
// solve on all lanes (Dd via wave-uniform global loads -> scalar pipe),
// batched w-store, then rank-16 trailing update from bf16 LDS tile.
// ---------------------------------------------------------------------------
__global__ __launch_bounds__(256) void k_solve(
    const float* __restrict__ base2, const u16* __restrict__ D11Tb,
    u16* __restrict__ P)
{
  __shared__ __align__(16) char Dst[2][8192];    // 16 rows x 256 bf16 cols
  __shared__ __align__(16) float sBuf[16][16];
  const int tid = threadIdx.x, l = tid & 63, w = tid >> 6;
  const int r = l >> 4, c = l & 15;
  const int row = blockIdx.x * 16 + w * 4 + r;
  const int rl = w * 4 + r;

  const float* brow = base2 + (size_t)row * 256;
  f32x4 A0 = *(const f32x4*)(brow + 8 * c);
  f32x4 A1 = *(const f32x4*)(brow + 8 * c + 4);
  f32x4 A2 = *(const f32x4*)(brow + 128 + 8 * c);
  f32x4 A3 = *(const f32x4*)(brow + 132 + 8 * c);

  const char* Dg = (const char*)D11Tb;
  const u32* DgU = (const u32*)D11Tb;
  u16* Prow = P + (size_t)row * 896 + 512;

  gl16(Dg + tid * 16, Dst[0] + tid * 16);
  gl16(Dg + 4096 + tid * 16, Dst[0] + 4096 + tid * 16);
  __syncthreads();

  for (int b = 0; b < 16; b++) {
    const int cur = b & 1;
    if (b < 15) {
      gl16(Dg + (b + 1) * 8192 + tid * 16, Dst[cur ^ 1] + tid * 16);
      gl16(Dg + (b + 1) * 8192 + 4096 + tid * 16, Dst[cur ^ 1] + 4096 + tid * 16);
    }
    // gather diag s values (2 owner lanes per row)
    if ((c >> 1) == (b & 7)) {
      const int off = (c & 1) * 8;
      if (b < 8) { *(f32x4*)&sBuf[rl][off] = A0; *(f32x4*)&sBuf[rl][off + 4] = A1; }
      else       { *(f32x4*)&sBuf[rl][off] = A2; *(f32x4*)&sBuf[rl][off + 4] = A3; }
    }
    float vv[16], wv[16];
    {
      f32x4 s0 = *(const f32x4*)&sBuf[rl][0];
      f32x4 s1 = *(const f32x4*)&sBuf[rl][4];
      f32x4 s2 = *(const f32x4*)&sBuf[rl][8];
      f32x4 s3 = *(const f32x4*)&sBuf[rl][12];
      vv[0]=s0.x; vv[1]=s0.y; vv[2]=s0.z; vv[3]=s0.w;
      vv[4]=s1.x; vv[5]=s1.y; vv[6]=s1.z; vv[7]=s1.w;
      vv[8]=s2.x; vv[9]=s2.y; vv[10]=s2.z; vv[11]=s2.w;
      vv[12]=s3.x; vv[13]=s3.y; vv[14]=s3.z; vv[15]=s3.w;
    }
    // redundant in-register diag solve; Dd via wave-uniform loads
    #pragma unroll
    for (int j = 0; j < 16; j++) {
      float v = vv[j];
      float e = __expf(2.f * v);
      float wj = 1.f - 2.f * __fdividef(1.f, e + 1.f);
      wv[j] = wj;
      if (j < 15) {
        u32 dr[8];
        #pragma unroll
        for (int t = 0; t < 8; t++)
          dr[t] = DgU[(16 * b + j) * 128 + 8 * b + t];
        #pragma unroll
        for (int k = j + 1; k < 16; k++) {
          u32 d = dr[k >> 1];
          float dv = b2f((u16)((k & 1) ? (d >> 16) : (d & 0xffffu)));
          vv[k] += wj * dv;
        }
      }
    }
    // batched w store (4 lanes, u16x4 each)
    if (c == 0) { u16x4 o; o.x=f2b(wv[0]); o.y=f2b(wv[1]); o.z=f2b(wv[2]); o.w=f2b(wv[3]); *(u16x4*)(Prow + 16*b) = o; }
    if (c == 1) { u16x4 o; o.x=f2b(wv[4]); o.y=f2b(wv[5]); o.z=f2b(wv[6]); o.w=f2b(wv[7]); *(u16x4*)(Prow + 16*b + 4) = o; }
    if (c == 2) { u16x4 o; o.x=f2b(wv[8]); o.y=f2b(wv[9]); o.z=f2b(wv[10]); o.w=f2b(wv[11]); *(u16x4*)(Prow + 16*b + 8) = o; }
    if (c == 3) { u16x4 o; o.x=f2b(wv[12]); o.y=f2b(wv[13]); o.z=f2b(wv[14]); o.w=f2b(wv[15]); *(u16x4*)(Prow + 16*b + 12) = o; }
    // trailing rank-16 update from bf16 LDS tile
    const char* tp = Dst[cur] + 16 * c;
    const bool lo = (c >= 2 * b + 2);
    const bool hi = (b < 8) || (c >= 2 * b - 14);
    #pragma unroll
    for (int j = 0; j < 16; j++) {
      const float wj = wv[j];
      if (lo) {
        u32x4 d = *(const u32x4*)(tp + j * 512);
        A0.x += wj * b2f((u16)(d.x & 0xffffu)); A0.y += wj * b2f((u16)(d.x >> 16));
        A0.z += wj * b2f((u16)(d.y & 0xffffu)); A0.w += wj * b2f((u16)(d.y >> 16));
        A1.x += wj * b2f((u16)(d.z & 0xffffu)); A1.y += wj * b2f((u16)(d.z >> 16));
        A1.z += wj * b2f((u16)(d.w & 0xffffu)); A1.w += wj * b2f((u16)(d.w >> 16));
      }
      if (hi) {
        u32x4 d = *(const u32x4*)(tp + j * 512 + 256);
        A2.x += wj * b2f((u16)(d.x & 0xffffu)); A2.y += wj * b2f((u16)(d.x >> 16));
        A2.z += wj * b2f((u16)(d.y & 0xffffu)); A2.w += wj * b2f((u16)(d.y >> 16));
        A3.x += wj * b2f((u16)(d.z & 0xffffu)); A3.y += wj * b2f((u16)(d.z >> 16));
        A3.z += wj * b2f((u16)(d.w & 0xffffu)); A3.w += wj * b2f((u16)(d.w >> 16));
      }
    }
    __syncthreads();
  }
}

// ---------------------------------------------------------------------------
extern "C" void kernel_launch(void* const* d_in, const int* in_sizes, int n_in,
                              void* d_out, int out_size, void* d_ws, size_t ws_size,
                              hipStream_t stream)
{
  const float* x   = (const float*)d_in[0];
  const float* u   = (const float*)d_in[1];
  const float* C1  = (const float*)d_in[2];
  const float* D11 = (const float*)d_in[3];
  const float* D12 = (const float*)d_in[4];
  const float* Lam = (const float*)d_in[5];
  const float* bv  = (const float*)d_in[6];
  const float* E   = (const float*)d_in[7];
  const float* F   = (const float*)d_in[8];
  const float* B1  = (const float*)d_in[9];
  const float* B2  = (const float*)d_in[10];
  const float* C2  = (const float*)d_in[11];
  const float* D21 = (const float*)d_in[12];

  char* ws = (char*)d_ws;
  u16*   P     = (u16*)(ws);                  // 8192x896 bf16
  u16*   Qt    = (u16*)(ws + 14680064);       // 640x896 bf16
  u16*   Rt    = (u16*)(ws + 15826944);       // 256x896 bf16
  float* base2 = (float*)(ws + 16285696);     // 8192x256 f32
  u16*   D11Tb = (u16*)(ws + 24674304);       // 256x256 bf16 = 131072
  u16*   Ebf   = (u16*)(ws + 24936448);
  u16*   Y0    = (u16*)(ws + 25460736);
  u16*   Z0    = (u16*)(ws + 25985024);
  u16*   T0T   = (u16*)(ws + 26509312);
  u16*   Y1    = (u16*)(ws + 27033600);
  u16*   McatT = (u16*)(ws + 29130752);       // 896x512 bf16
  float* invLam= (float*)(ws + 30048256);

  float* dxOut = (float*)d_out;
  float* yOut  = dxOut + (size_t)8192 * 512;

  k_prepc<<<7489, 256, 0, stream>>>(x, u, C1, D12, Lam, E, C2, D21,
                                    Ebf, Y0, Qt, Rt, invLam, P);
  k_transp<<<768, 256, 0, stream>>>(E, F, B1, B2, D11, Lam, Z0, McatT, D11Tb);

  GemmArgs bb{}; bb.A = P; bb.B = Rt; bb.K = 896; bb.outF = base2;
  bb.bv = bv; bb.iLam = invLam;
  gemm_nt<0><<<dim3(2, 64), 256, 0, stream>>>(bb);           // base2

  k_solve<<<512, 256, 0, stream>>>(base2, D11Tb, P);         // w -> P[:,512:768]

  GemmArgs a{}; a.A = Ebf; a.B = Z0; a.K = 512; a.outBT = T0T;
  gemm64<3><<<dim3(8, 8), 256, 0, stream>>>(a);              // T0^T = (E@Y0)^T

  GemmArgs b{}; b.A = Y0; b.B = T0T; b.K = 512; b.outB = Y1; b.ldB = 512;
  b.Yprev = Y0;
  gemm64<4><<<dim3(8, 8), 256, 0, stream>>>(b);              // Y1 = 2Y0 - Y0@(E@Y0)

  GemmArgs qq{}; qq.A = Y1; qq.B = McatT; qq.K = 512; qq.outB = Qt; qq.ldB = 896;
  gemm64<2><<<dim3(14, 8), 256, 0, stream>>>(qq);            // Qt[0:512] = Einv@[F B1 B2]

  GemmArgs ff{}; ff.A = P; ff.B = Qt; ff.K = 896; ff.dxOut = dxOut; ff.yOut = yOut;
  gemm_nt<1><<<dim3(5, 64), 256, 0, stream>>>(ff);           // [dx | y]
  (void)in_sizes; (void)n_in; (void)out_size; (void)ws_size;
}

// Round 5
// 135.560 us; speedup vs baseline: 1.2025x; 1.2025x over previous
//
#include <hip/hip_runtime.h>

typedef unsigned short u16;
typedef unsigned int   u32;
typedef __attribute__((ext_vector_type(8))) __bf16 bf16x8;
typedef __attribute__((ext_vector_type(4))) float  f32x4;
typedef __attribute__((ext_vector_type(4))) u16    u16x4;
typedef __attribute__((ext_vector_type(2))) u32    u32x2;
typedef __attribute__((ext_vector_type(4))) u32    u32x4;

#define DEV __device__ __forceinline__

DEV u16 f2b(float f){ union{float f;u32 u;}a; a.f=f; u32 r=a.u + 0x7FFFu + ((a.u>>16)&1u); return (u16)(r>>16); }
DEV float b2f(u16 h){ union{u32 u;float f;}a; a.u=((u32)h)<<16; return a.f; }

typedef __attribute__((address_space(1))) void* gp1;
typedef __attribute__((address_space(3))) void* lp3;
DEV void gl16(const void* g, void* l){
  __builtin_amdgcn_global_load_lds((gp1)g, (lp3)l, 16, 0, 0);
}

// ---------------------------------------------------------------------------
// prep: Ebf/Y0, Qt y-rows, Rt, invLam, Ddg ([sb][row][k2] bf16 = D11/lam),
// DdiagTf ([sb][k2][n2] f32, strictly-upper else 0), P = [x|.|u] bf16
// ---------------------------------------------------------------------------
__global__ __launch_bounds__(256) void k_prepc(
    const float* __restrict__ x,  const float* __restrict__ u,
    const float* __restrict__ C1, const float* __restrict__ D11,
    const float* __restrict__ D12, const float* __restrict__ Lam,
    const float* __restrict__ E,  const float* __restrict__ C2,
    const float* __restrict__ D21,
    u16* Ebf, u16* Y0, u16* Qt, u16* Rt, float* invLam,
    u16* Ddg, float* DdiagTf, u16* P)
{
  int idx = blockIdx.x * 256 + threadIdx.x;
  if (idx < 262144) {                       // Ebf, Y0 = 2I-E
    int i = idx >> 9, j = idx & 511;
    float e = E[idx];
    Ebf[idx] = f2b(e);
    float dij = (i == j) ? 2.f : 0.f;
    Y0[idx] = f2b(dij - e);
    return;
  }
  idx -= 262144;
  if (idx < 114688) {                       // Qt rows 512..639 (y part)
    int j = idx / 896, k = idx - j * 896;
    float v = (k < 512) ? C2[j * 512 + k]
              : (k < 768 ? D21[j * 256 + (k - 512)] : 0.f);
    Qt[(size_t)(512 + j) * 896 + k] = f2b(v);
    return;
  }
  idx -= 114688;
  if (idx < 229376) {                       // Rt (256x896): [C1 | 0 | D12]
    int n = idx / 896, k = idx - n * 896;
    float v = (k < 512) ? C1[n * 512 + k]
              : (k < 768 ? 0.f : D12[n * 128 + (k - 768)]);
    Rt[idx] = f2b(v);
    return;
  }
  idx -= 229376;
  if (idx < 256) { invLam[idx] = 1.f / Lam[idx * 257]; return; }
  idx -= 256;
  if (idx < 65536) {                        // Ddg[sb][row][k2]
    int sb = idx >> 13, rown = (idx >> 5) & 255, k2 = idx & 31;
    Ddg[idx] = f2b(D11[rown * 256 + sb * 32 + k2] * (1.f / Lam[rown * 257]));
    return;
  }
  idx -= 65536;
  if (idx < 8192) {                         // DdiagTf[sb][k2][n2]
    int sb = idx >> 10, k2 = (idx >> 5) & 31, n2 = idx & 31;
    float v = 0.f;
    if (n2 > k2) {
      int n = sb * 32 + n2;
      v = D11[n * 256 + sb * 32 + k2] * (1.f / Lam[n * 257]);
    }
    DdiagTf[idx] = v;
    return;
  }
  idx -= 8192;
  {                                         // P = [x | . | u] bf16
    int b = idx / 160, t = idx - b * 160;
    f32x4 s; u16* dst;
    if (t < 128) { s = *(const f32x4*)(x + (size_t)b * 512 + t * 4); dst = P + (size_t)b * 896 + t * 4; }
    else         { s = *(const f32x4*)(u + (size_t)b * 128 + (t - 128) * 4); dst = P + (size_t)b * 896 + 768 + (t - 128) * 4; }
    u16x4 o; o.x = f2b(s.x); o.y = f2b(s.y); o.z = f2b(s.z); o.w = f2b(s.w);
    *(u16x4*)dst = o;
  }
}

// ---------------------------------------------------------------------------
// tiled transposes: Z0 = 2I - E^T, McatT = [F;B1;B2]^T
// ---------------------------------------------------------------------------
__global__ __launch_bounds__(256) void k_transp(
    const float* __restrict__ E,  const float* __restrict__ F,
    const float* __restrict__ B1, const float* __restrict__ B2,
    u16* Z0, u16* McatT)
{
  __shared__ float t[32][33];
  int bid = blockIdx.x;
  const int tx = threadIdx.x & 31, ty = threadIdx.x >> 5;

  const float* src; u16* dst; int srcC, nA, task;
  if (bid < 256)      { task = 0; src = E;   srcC = 512; dst = Z0;    nA = 16; }
  else if (bid < 512) { task = 1; src = F;   srcC = 512; dst = McatT; nA = 16; bid -= 256; }
  else if (bid < 640) { task = 2; src = B1;  srcC = 256; dst = McatT + (size_t)512 * 512; nA = 8;  bid -= 512; }
  else                { task = 3; src = B2;  srcC = 128; dst = McatT + (size_t)768 * 512; nA = 4;  bid -= 640; }

  const int a0 = (bid % nA) * 32;
  const int b0 = (bid / nA) * 32;

  #pragma unroll
  for (int k = 0; k < 4; k++) {
    int srow = b0 + ty + 8 * k;
    t[ty + 8 * k][tx] = src[(size_t)srow * srcC + a0 + tx];
  }
  __syncthreads();
  #pragma unroll
  for (int k = 0; k < 4; k++) {
    int drow = a0 + ty + 8 * k, dcol = b0 + tx;
    float v = t[tx][ty + 8 * k];
    if (task == 0) v = ((drow == dcol) ? 2.f : 0.f) - v;
    dst[(size_t)drow * 512 + dcol] = f2b(v);
  }
}

// ---------------------------------------------------------------------------
// NT bf16 MFMA GEMM, 128x128 tile, BK=32, 256 threads (2x2 waves, 64x64/wave)
// ---------------------------------------------------------------------------
struct GemmArgs {
  const u16* A; const u16* B; int K;
  float* outF;
  u16* outB; int ldB;
  u16* outBT;
  const u16* Yprev;
  const float* bv; const float* iLam;
  float* dxOut; float* yOut;
};

template<int EPI>
__global__ __launch_bounds__(256) void gemm_nt(GemmArgs g)
{
  __shared__ __align__(16) u16 As[128 * 32];
  __shared__ __align__(16) u16 Bs[128 * 32];
  const int tid = threadIdx.x;
  const int l = tid & 63, w = tid >> 6;
  const int bm = blockIdx.y, bn = blockIdx.x;
  const int K = g.K;
  const size_t rowb = (size_t)K * 2;
  const char* Ab = (const char*)g.A + (size_t)bm * 128 * rowb;
  const char* Bb = (const char*)g.B + (size_t)bn * 128 * rowb;
  const int o1 = w * 1024 + l * 16, o2 = o1 + 4096;
  const int r1 = o1 >> 6, r2 = o2 >> 6;
  const int c1 = (((o1 >> 4) ^ r1) & 3) << 4;
  const int c2 = (((o2 >> 4) ^ r2) & 3) << 4;
  char* AsB = (char*)As; char* BsB = (char*)Bs;
  const int wm = w >> 1, wn = w & 1;
  const int lr = l & 15, lk = l >> 4;
  const int slot = ((lk ^ lr) & 3) << 4;

  f32x4 acc[4][4];
  const f32x4 zz = {0.f, 0.f, 0.f, 0.f};
  #pragma unroll
  for (int i = 0; i < 4; i++)
    #pragma unroll
    for (int j = 0; j < 4; j++) acc[i][j] = zz;

  for (int k0 = 0; k0 < K; k0 += 32) {
    gl16(Ab + (size_t)r1 * rowb + k0 * 2 + c1, AsB + o1);
    gl16(Ab + (size_t)r2 * rowb + k0 * 2 + c2, AsB + o2);
    gl16(Bb + (size_t)r1 * rowb + k0 * 2 + c1, BsB + o1);
    gl16(Bb + (size_t)r2 * rowb + k0 * 2 + c2, BsB + o2);
    __syncthreads();
    bf16x8 af[4], bfv[4];
    #pragma unroll
    for (int mi = 0; mi < 4; mi++)
      af[mi] = *(const bf16x8*)(AsB + (wm * 64 + mi * 16 + lr) * 64 + slot);
    #pragma unroll
    for (int ni = 0; ni < 4; ni++)
      bfv[ni] = *(const bf16x8*)(BsB + (wn * 64 + ni * 16 + lr) * 64 + slot);
    #pragma unroll
    for (int mi = 0; mi < 4; mi++)
      #pragma unroll
      for (int ni = 0; ni < 4; ni++)
        acc[mi][ni] = __builtin_amdgcn_mfma_f32_16x16x32_bf16(af[mi], bfv[ni], acc[mi][ni], 0, 0, 0);
    __syncthreads();
  }

  #pragma unroll
  for (int mi = 0; mi < 4; mi++) {
    #pragma unroll
    for (int ni = 0; ni < 4; ni++) {
      const int row0 = bm * 128 + wm * 64 + mi * 16 + lk * 4;
      const int col  = bn * 128 + wn * 64 + ni * 16 + lr;
      if (EPI == 0) {
        const float bvc = g.bv[col], il = g.iLam[col];
        #pragma unroll
        for (int r = 0; r < 4; r++)
          g.outF[(size_t)(row0 + r) * 256 + col] = (acc[mi][ni][r] + bvc) * il;
      } else if (EPI == 1) {
        #pragma unroll
        for (int r = 0; r < 4; r++) {
          float v = acc[mi][ni][r];
          if (col < 512) g.dxOut[(size_t)(row0 + r) * 512 + col] = v;
          else           g.yOut[(size_t)(row0 + r) * 128 + (col - 512)] = v;
        }
      }
    }
  }
}

// ---------------------------------------------------------------------------
// NT bf16 MFMA GEMM, 64x64 tile for the small 512-wide chain
// ---------------------------------------------------------------------------
template<int EPI>
__global__ __launch_bounds__(256) void gemm64(GemmArgs g)
{
  __shared__ __align__(16) u16 As[64 * 32];
  __shared__ __align__(16) u16 Bs[64 * 32];
  const int tid = threadIdx.x;
  const int l = tid & 63, w = tid >> 6;
  const int bm = blockIdx.y, bn = blockIdx.x;
  const int K = g.K;
  const size_t rowb = (size_t)K * 2;
  const char* Ab = (const char*)g.A + (size_t)bm * 64 * rowb;
  const char* Bb = (const char*)g.B + (size_t)bn * 64 * rowb;
  const int o = tid * 16;
  const int r0 = o >> 6;
  const int cs = (((o >> 4) ^ r0) & 3) << 4;
  char* AsB = (char*)As; char* BsB = (char*)Bs;
  const int wm = w >> 1, wn = w & 1;
  const int lr = l & 15, lk = l >> 4;
  const int slot = ((lk ^ lr) & 3) << 4;

  f32x4 acc[2][2];
  const f32x4 zz = {0.f, 0.f, 0.f, 0.f};
  acc[0][0] = zz; acc[0][1] = zz; acc[1][0] = zz; acc[1][1] = zz;

  for (int k0 = 0; k0 < K; k0 += 32) {
    gl16(Ab + (size_t)r0 * rowb + k0 * 2 + cs, AsB + o);
    gl16(Bb + (size_t)r0 * rowb + k0 * 2 + cs, BsB + o);
    __syncthreads();
    bf16x8 af[2], bfv[2];
    #pragma unroll
    for (int mi = 0; mi < 2; mi++)
      af[mi] = *(const bf16x8*)(AsB + (wm * 32 + mi * 16 + lr) * 64 + slot);
    #pragma unroll
    for (int ni = 0; ni < 2; ni++)
      bfv[ni] = *(const bf16x8*)(BsB + (wn * 32 + ni * 16 + lr) * 64 + slot);
    #pragma unroll
    for (int mi = 0; mi < 2; mi++)
      #pragma unroll
      for (int ni = 0; ni < 2; ni++)
        acc[mi][ni] = __builtin_amdgcn_mfma_f32_16x16x32_bf16(af[mi], bfv[ni], acc[mi][ni], 0, 0, 0);
    __syncthreads();
  }

  #pragma unroll
  for (int mi = 0; mi < 2; mi++) {
    #pragma unroll
    for (int ni = 0; ni < 2; ni++) {
      const int row0 = bm * 64 + wm * 32 + mi * 16 + lk * 4;
      const int col  = bn * 64 + wn * 32 + ni * 16 + lr;
      if (EPI == 2) {
        #pragma unroll
        for (int r = 0; r < 4; r++)
          g.outB[(size_t)(row0 + r) * g.ldB + col] = f2b(acc[mi][ni][r]);
      } else if (EPI == 3) {
        #pragma unroll
        for (int r = 0; r < 4; r++)
          g.outBT[(size_t)col * 512 + (row0 + r)] = f2b(acc[mi][ni][r]);
      } else if (EPI == 4) {
        #pragma unroll
        for (int r = 0; r < 4; r++) {
          int row = row0 + r;
          float d = 2.f * b2f(g.Yprev[row * 512 + col]) - acc[mi][ni][r];
          g.outB[(size_t)row * 512 + col] = f2b(d);
        }
      }
    }
  }
}

// ---------------------------------------------------------------------------
// tanh recurrence: MFMA-based blocked forward substitution.
// 256 blocks x 128 thr (2 waves); wave owns 16 rows x 256 cols.
// State layout (swapped-operand MFMA): batchrow = lane&15, statecol(per 16-
// tile) = (lane>>4)*4 + reg  -> st[16] f32x4 = exactly MFMA C-fragments.
// Per 32-col superblock: 32-step serial diag solve (shfl broadcast + f32
// zero-padded diag blocks, branch-free) then trailing mfma_16x16x32 updates
// with A = D~ slab from LDS (XOR-swizzled), B = packed bf16 w-fragment.
// ---------------------------------------------------------------------------
__global__ __launch_bounds__(128) void k_solve(
    const float* __restrict__ base2, const u16* __restrict__ Ddg,
    const float* __restrict__ DdiagTf, u16* __restrict__ P)
{
  __shared__ __align__(16) char DdL[2][16384];   // D~ slab [row][64B], swz
  __shared__ __align__(16) float DtL[8192];      // diag blocks [sb][k2][n2]
  __shared__ __align__(16) u32 wL[2][16][16];    // per-wave w shuffle buffer
  const int tid = threadIdx.x;
  const int l = tid & 63, w = tid >> 6;
  const int r = l & 15, g = l >> 4;
  const int row = blockIdx.x * 32 + w * 16 + r;

  const char* DtG = (const char*)DdiagTf;
  #pragma unroll
  for (int i = 0; i < 16; i++)
    gl16(DtG + i * 2048 + tid * 16, (char*)DtL + i * 2048 + tid * 16);
  const char* DgG = (const char*)Ddg;
  #pragma unroll
  for (int i = 0; i < 8; i++) {
    int o = tid * 16 + i * 2048;
    int rw = o >> 6, sl = o & 63;
    gl16(DgG + rw * 64 + (sl ^ ((rw & 3) << 4)), DdL[0] + o);
  }

  f32x4 st[16];
  const float* bp = base2 + (size_t)row * 256 + g * 4;
  #pragma unroll
  for (int t = 0; t < 16; t++) st[t] = *(const f32x4*)(bp + t * 16);

  u16* Pr = P + (size_t)row * 896 + 512;
  char* wb = (char*)&wL[w][0][0];
  __syncthreads();

  #pragma unroll
  for (int sb = 0; sb < 8; sb++) {
    if (sb < 7) {                                // prefetch next slab
      const char* src = DgG + (sb + 1) * 16384;
      char* dst = DdL[(sb + 1) & 1];
      #pragma unroll
      for (int i = 0; i < 8; i++) {
        int o = tid * 16 + i * 2048;
        int rw = o >> 6, sl = o & 63;
        gl16(src + rw * 64 + (sl ^ ((rw & 3) << 4)), dst + o);
      }
    }
    float wk0[4] = {0.f, 0.f, 0.f, 0.f};
    float wk1[4] = {0.f, 0.f, 0.f, 0.f};
    const float* dtb = DtL + sb * 1024;
    #pragma unroll
    for (int k2 = 0; k2 < 32; k2++) {
      const int T = k2 >> 4, cwi = k2 & 15, go = cwi >> 2, e = cwi & 3;
      f32x4 sv = (T == 0) ? st[2 * sb] : st[2 * sb + 1];
      float vsel = (e == 0) ? sv.x : (e == 1) ? sv.y : (e == 2) ? sv.z : sv.w;
      float v = __shfl(vsel, r + (go << 4), 64);
      float ex = __expf(2.f * v);
      float wv = 1.f - 2.f * __fdividef(1.f, ex + 1.f);
      if (T == 0) wk0[e] = (g == go) ? wv : wk0[e];
      else        wk1[e] = (g == go) ? wv : wk1[e];
      const float* dp = dtb + k2 * 32 + g * 4;
      if (T == 0) {                              // tile0 gets updates only pre-16
        f32x4 d0 = *(const f32x4*)dp;
        st[2 * sb] += wv * d0;
      }
      f32x4 d1 = *(const f32x4*)(dp + 16);       // zero-padded below/diag
      st[2 * sb + 1] += wv * d1;
    }
    // pack w -> bf16 pairs; store to P and to per-wave shuffle buffer
    u32 pk0 = (u32)f2b(wk0[0]) | ((u32)f2b(wk0[1]) << 16);
    u32 pk1 = (u32)f2b(wk0[2]) | ((u32)f2b(wk0[3]) << 16);
    u32 pk2 = (u32)f2b(wk1[0]) | ((u32)f2b(wk1[1]) << 16);
    u32 pk3 = (u32)f2b(wk1[2]) | ((u32)f2b(wk1[3]) << 16);
    u32x2 s0; s0.x = pk0; s0.y = pk1;
    u32x2 s1; s1.x = pk2; s1.y = pk3;
    *(u32x2*)(Pr + 32 * sb + 4 * g) = s0;
    *(u32x2*)(Pr + 32 * sb + 16 + 4 * g) = s1;
    *(u32x2*)(wb + r * 64 + ((g * 8) ^ ((r & 3) << 4))) = s0;
    *(u32x2*)(wb + r * 64 + ((32 + g * 8) ^ ((r & 3) << 4))) = s1;
    u32x4 bw = *(const u32x4*)(wb + r * 64 + ((g * 16) ^ ((r & 3) << 4)));
    union { u32x4 uu; bf16x8 bb; } cv; cv.uu = bw;
    // trailing updates: one K=32 MFMA per remaining 16-col tile
    #pragma unroll
    for (int t = 2 * sb + 2; t < 16; t++) {
      const int rowD = t * 16 + r;
      const char* ap = DdL[sb & 1] + rowD * 64 + ((g * 16) ^ ((rowD & 3) << 4));
      bf16x8 Af = *(const bf16x8*)ap;
      st[t] = __builtin_amdgcn_mfma_f32_16x16x32_bf16(Af, cv.bb, st[t], 0, 0, 0);
    }
    __syncthreads();
  }
}

// ---------------------------------------------------------------------------
extern "C" void kernel_launch(void* const* d_in, const int* in_sizes, int n_in,
                              void* d_out, int out_size, void* d_ws, size_t ws_size,
                              hipStream_t stream)
{
  const float* x   = (const float*)d_in[0];
  const float* u   = (const float*)d_in[1];
  const float* C1  = (const float*)d_in[2];
  const float* D11 = (const float*)d_in[3];
  const float* D12 = (const float*)d_in[4];
  const float* Lam = (const float*)d_in[5];
  const float* bv  = (const float*)d_in[6];
  const float* E   = (const float*)d_in[7];
  const float* F   = (const float*)d_in[8];
  const float* B1  = (const float*)d_in[9];
  const float* B2  = (const float*)d_in[10];
  const float* C2  = (const float*)d_in[11];
  const float* D21 = (const float*)d_in[12];

  char* ws = (char*)d_ws;
  u16*   P      = (u16*)(ws);                 // 14,680,064
  u16*   Qt     = (u16*)(ws + 14680064);      //  1,146,880
  u16*   Rt     = (u16*)(ws + 15826944);      //    458,752
  float* base2  = (float*)(ws + 16285696);    //  8,388,608
  u16*   Ddg    = (u16*)(ws + 24674304);      //    131,072
  float* DdiagTf= (float*)(ws + 24805376);    //     32,768
  u16*   Ebf    = (u16*)(ws + 24838144);      //    524,288
  u16*   Y0     = (u16*)(ws + 25362432);
  u16*   Z0     = (u16*)(ws + 25886720);
  u16*   T0T    = (u16*)(ws + 26411008);
  u16*   Y1     = (u16*)(ws + 26935296);
  u16*   McatT  = (u16*)(ws + 27459584);      //    917,504
  float* invLam = (float*)(ws + 28377088);

  float* dxOut = (float*)d_out;
  float* yOut  = dxOut + (size_t)8192 * 512;

  k_prepc<<<7777, 256, 0, stream>>>(x, u, C1, D11, D12, Lam, E, C2, D21,
                                    Ebf, Y0, Qt, Rt, invLam, Ddg, DdiagTf, P);
  k_transp<<<704, 256, 0, stream>>>(E, F, B1, B2, Z0, McatT);

  GemmArgs bb{}; bb.A = P; bb.B = Rt; bb.K = 896; bb.outF = base2;
  bb.bv = bv; bb.iLam = invLam;
  gemm_nt<0><<<dim3(2, 64), 256, 0, stream>>>(bb);           // base2

  k_solve<<<256, 128, 0, stream>>>(base2, Ddg, DdiagTf, P);  // w -> P[:,512:768]

  GemmArgs a{}; a.A = Ebf; a.B = Z0; a.K = 512; a.outBT = T0T;
  gemm64<3><<<dim3(8, 8), 256, 0, stream>>>(a);              // T0^T = (E@Y0)^T

  GemmArgs b{}; b.A = Y0; b.B = T0T; b.K = 512; b.outB = Y1; b.ldB = 512;
  b.Yprev = Y0;
  gemm64<4><<<dim3(8, 8), 256, 0, stream>>>(b);              // Y1 = 2Y0 - Y0@(E@Y0)

  GemmArgs qq{}; qq.A = Y1; qq.B = McatT; qq.K = 512; qq.outB = Qt; qq.ldB = 896;
  gemm64<2><<<dim3(14, 8), 256, 0, stream>>>(qq);            // Qt[0:512] = Einv@[F B1 B2]

  GemmArgs ff{}; ff.A = P; ff.B = Qt; ff.K = 896; ff.dxOut = dxOut; ff.yOut = yOut;
  gemm_nt<1><<<dim3(5, 64), 256, 0, stream>>>(ff);           // [dx | y]
  (void)in_sizes; (void)n_in; (void)out_size; (void)ws_size;
}

// Round 6
// 120.483 us; speedup vs baseline: 1.3530x; 1.1251x over previous
//
#include <hip/hip_runtime.h>

typedef unsigned short u16;
typedef unsigned int   u32;
typedef __attribute__((ext_vector_type(8))) __bf16 bf16x8;
typedef __attribute__((ext_vector_type(4))) float  f32x4;
typedef __attribute__((ext_vector_type(4))) u16    u16x4;
typedef __attribute__((ext_vector_type(4))) u32    u32x4;

#define DEV __device__ __forceinline__

DEV u16 f2b(float f){ union{float f;u32 u;}a; a.f=f; u32 r=a.u + 0x7FFFu + ((a.u>>16)&1u); return (u16)(r>>16); }
DEV float b2f(u16 h){ union{u32 u;float f;}a; a.u=((u32)h)<<16; return a.f; }

typedef __attribute__((address_space(1))) void* gp1;
typedef __attribute__((address_space(3))) void* lp3;
DEV void gl16(const void* g, void* l){
  __builtin_amdgcn_global_load_lds((gp1)g, (lp3)l, 16, 0, 0);
}

// ---------------------------------------------------------------------------
// fused prep: transposes (blocks 0..703) + elementwise prep (rest)
// Ddg2: per-(sb,tile) 1KB MFMA-A fragment layout: [(sb*16+t)*64 + l]*8 + j
//       holds D~[t*16 + (l&15)][sb*32 + (l>>4)*8 + j],  D~[n][k]=D11[n][k]/lam[n]
// Dt16: [T][k2][n2] f32, = D~[T*16+n2][T*16+k2] if n2>k2 else 0
// ---------------------------------------------------------------------------
__global__ __launch_bounds__(256) void k_prepc(
    const float* __restrict__ x,  const float* __restrict__ u,
    const float* __restrict__ C1, const float* __restrict__ D11,
    const float* __restrict__ D12, const float* __restrict__ Lam,
    const float* __restrict__ E,  const float* __restrict__ F,
    const float* __restrict__ B1, const float* __restrict__ B2,
    const float* __restrict__ C2, const float* __restrict__ D21,
    u16* Ebf, u16* Y0, u16* Z0, u16* McatT, u16* Qt, u16* Rt,
    float* invLam, u16* Ddg2, float* Dt16, u16* P)
{
  if (blockIdx.x < 704) {                   // tiled transposes
    __shared__ float t[32][33];
    int bid = blockIdx.x;
    const int tx = threadIdx.x & 31, ty = threadIdx.x >> 5;
    const float* src; u16* dst; int srcC, nA, task;
    if (bid < 256)      { task = 0; src = E;   srcC = 512; dst = Z0;    nA = 16; }
    else if (bid < 512) { task = 1; src = F;   srcC = 512; dst = McatT; nA = 16; bid -= 256; }
    else if (bid < 640) { task = 2; src = B1;  srcC = 256; dst = McatT + (size_t)512 * 512; nA = 8;  bid -= 512; }
    else                { task = 3; src = B2;  srcC = 128; dst = McatT + (size_t)768 * 512; nA = 4;  bid -= 640; }
    const int a0 = (bid % nA) * 32;
    const int b0 = (bid / nA) * 32;
    #pragma unroll
    for (int k = 0; k < 4; k++) {
      int srow = b0 + ty + 8 * k;
      t[ty + 8 * k][tx] = src[(size_t)srow * srcC + a0 + tx];
    }
    __syncthreads();
    #pragma unroll
    for (int k = 0; k < 4; k++) {
      int drow = a0 + ty + 8 * k, dcol = b0 + tx;
      float v = t[tx][ty + 8 * k];
      if (task == 0) v = ((drow == dcol) ? 2.f : 0.f) - v;
      dst[(size_t)drow * 512 + dcol] = f2b(v);
    }
    return;
  }
  int idx = (blockIdx.x - 704) * 256 + threadIdx.x;
  if (idx < 262144) {                       // Ebf, Y0 = 2I-E
    int i = idx >> 9, j = idx & 511;
    float e = E[idx];
    Ebf[idx] = f2b(e);
    float dij = (i == j) ? 2.f : 0.f;
    Y0[idx] = f2b(dij - e);
    return;
  }
  idx -= 262144;
  if (idx < 114688) {                       // Qt rows 512..639 (y part)
    int j = idx / 896, k = idx - j * 896;
    float v = (k < 512) ? C2[j * 512 + k]
              : (k < 768 ? D21[j * 256 + (k - 512)] : 0.f);
    Qt[(size_t)(512 + j) * 896 + k] = f2b(v);
    return;
  }
  idx -= 114688;
  if (idx < 229376) {                       // Rt (256x896): [C1 | 0 | D12]
    int n = idx / 896, k = idx - n * 896;
    float v = (k < 512) ? C1[n * 512 + k]
              : (k < 768 ? 0.f : D12[n * 128 + (k - 768)]);
    Rt[idx] = f2b(v);
    return;
  }
  idx -= 229376;
  if (idx < 256) { invLam[idx] = 1.f / Lam[idx * 257]; return; }
  idx -= 256;
  if (idx < 65536) {                        // Ddg2 fragment layout
    int sb = idx >> 13, t = (idx >> 9) & 15, l = (idx >> 3) & 63, j = idx & 7;
    int r = l & 15, g = l >> 4;
    int n = t * 16 + r, k = sb * 32 + g * 8 + j;
    Ddg2[idx] = f2b(D11[n * 256 + k] * (1.f / Lam[n * 257]));
    return;
  }
  idx -= 65536;
  if (idx < 4096) {                         // Dt16 triangular diag blocks
    int T = idx >> 8, k2 = (idx >> 4) & 15, n2 = idx & 15;
    float v = 0.f;
    if (n2 > k2) {
      int n = T * 16 + n2;
      v = D11[n * 256 + T * 16 + k2] * (1.f / Lam[n * 257]);
    }
    Dt16[idx] = v;
    return;
  }
  idx -= 4096;
  {                                         // P = [x | . | u] bf16
    int b = idx / 160, t = idx - b * 160;
    f32x4 s; u16* dst;
    if (t < 128) { s = *(const f32x4*)(x + (size_t)b * 512 + t * 4); dst = P + (size_t)b * 896 + t * 4; }
    else         { s = *(const f32x4*)(u + (size_t)b * 128 + (t - 128) * 4); dst = P + (size_t)b * 896 + 768 + (t - 128) * 4; }
    u16x4 o; o.x = f2b(s.x); o.y = f2b(s.y); o.z = f2b(s.z); o.w = f2b(s.w);
    *(u16x4*)dst = o;
  }
}

// ---------------------------------------------------------------------------
// NT bf16 MFMA GEMM, 128x128 tile, BK=32, 256 threads (2x2 waves, 64x64/wave)
// ---------------------------------------------------------------------------
struct GemmArgs {
  const u16* A; const u16* B; int K;
  float* outF;
  u16* outB; int ldB;
  u16* outBT;
  const u16* Yprev;
  const float* bv; const float* iLam;
  float* dxOut; float* yOut;
};

template<int EPI>
__global__ __launch_bounds__(256) void gemm_nt(GemmArgs g)
{
  __shared__ __align__(16) u16 As[128 * 32];
  __shared__ __align__(16) u16 Bs[128 * 32];
  const int tid = threadIdx.x;
  const int l = tid & 63, w = tid >> 6;
  const int bm = blockIdx.y, bn = blockIdx.x;
  const int K = g.K;
  const size_t rowb = (size_t)K * 2;
  const char* Ab = (const char*)g.A + (size_t)bm * 128 * rowb;
  const char* Bb = (const char*)g.B + (size_t)bn * 128 * rowb;
  const int o1 = w * 1024 + l * 16, o2 = o1 + 4096;
  const int r1 = o1 >> 6, r2 = o2 >> 6;
  const int c1 = (((o1 >> 4) ^ r1) & 3) << 4;
  const int c2 = (((o2 >> 4) ^ r2) & 3) << 4;
  char* AsB = (char*)As; char* BsB = (char*)Bs;
  const int wm = w >> 1, wn = w & 1;
  const int lr = l & 15, lk = l >> 4;
  const int slot = ((lk ^ lr) & 3) << 4;

  f32x4 acc[4][4];
  const f32x4 zz = {0.f, 0.f, 0.f, 0.f};
  #pragma unroll
  for (int i = 0; i < 4; i++)
    #pragma unroll
    for (int j = 0; j < 4; j++) acc[i][j] = zz;

  for (int k0 = 0; k0 < K; k0 += 32) {
    gl16(Ab + (size_t)r1 * rowb + k0 * 2 + c1, AsB + o1);
    gl16(Ab + (size_t)r2 * rowb + k0 * 2 + c2, AsB + o2);
    gl16(Bb + (size_t)r1 * rowb + k0 * 2 + c1, BsB + o1);
    gl16(Bb + (size_t)r2 * rowb + k0 * 2 + c2, BsB + o2);
    __syncthreads();
    bf16x8 af[4], bfv[4];
    #pragma unroll
    for (int mi = 0; mi < 4; mi++)
      af[mi] = *(const bf16x8*)(AsB + (wm * 64 + mi * 16 + lr) * 64 + slot);
    #pragma unroll
    for (int ni = 0; ni < 4; ni++)
      bfv[ni] = *(const bf16x8*)(BsB + (wn * 64 + ni * 16 + lr) * 64 + slot);
    #pragma unroll
    for (int mi = 0; mi < 4; mi++)
      #pragma unroll
      for (int ni = 0; ni < 4; ni++)
        acc[mi][ni] = __builtin_amdgcn_mfma_f32_16x16x32_bf16(af[mi], bfv[ni], acc[mi][ni], 0, 0, 0);
    __syncthreads();
  }

  #pragma unroll
  for (int mi = 0; mi < 4; mi++) {
    #pragma unroll
    for (int ni = 0; ni < 4; ni++) {
      const int row0 = bm * 128 + wm * 64 + mi * 16 + lk * 4;
      const int col  = bn * 128 + wn * 64 + ni * 16 + lr;
      if (EPI == 0) {
        const float bvc = g.bv[col], il = g.iLam[col];
        #pragma unroll
        for (int r = 0; r < 4; r++)
          g.outF[(size_t)(row0 + r) * 256 + col] = (acc[mi][ni][r] + bvc) * il;
      } else if (EPI == 1) {
        #pragma unroll
        for (int r = 0; r < 4; r++) {
          float v = acc[mi][ni][r];
          if (col < 512) g.dxOut[(size_t)(row0 + r) * 512 + col] = v;
          else           g.yOut[(size_t)(row0 + r) * 128 + (col - 512)] = v;
        }
      }
    }
  }
}

// ---------------------------------------------------------------------------
// NT bf16 MFMA GEMM, 64x64 tile (device body, callable from fused kernels)
// ---------------------------------------------------------------------------
template<int EPI>
DEV void gemm64_body(const GemmArgs& g, int bm, int bn, u16* As, u16* Bs)
{
  const int tid = threadIdx.x;
  const int l = tid & 63, w = tid >> 6;
  const int K = g.K;
  const size_t rowb = (size_t)K * 2;
  const char* Ab = (const char*)g.A + (size_t)bm * 64 * rowb;
  const char* Bb = (const char*)g.B + (size_t)bn * 64 * rowb;
  const int o = tid * 16;
  const int r0 = o >> 6;
  const int cs = (((o >> 4) ^ r0) & 3) << 4;
  char* AsB = (char*)As; char* BsB = (char*)Bs;
  const int wm = w >> 1, wn = w & 1;
  const int lr = l & 15, lk = l >> 4;
  const int slot = ((lk ^ lr) & 3) << 4;

  f32x4 acc[2][2];
  const f32x4 zz = {0.f, 0.f, 0.f, 0.f};
  acc[0][0] = zz; acc[0][1] = zz; acc[1][0] = zz; acc[1][1] = zz;

  for (int k0 = 0; k0 < K; k0 += 32) {
    gl16(Ab + (size_t)r0 * rowb + k0 * 2 + cs, AsB + o);
    gl16(Bb + (size_t)r0 * rowb + k0 * 2 + cs, BsB + o);
    __syncthreads();
    bf16x8 af[2], bfv[2];
    #pragma unroll
    for (int mi = 0; mi < 2; mi++)
      af[mi] = *(const bf16x8*)(AsB + (wm * 32 + mi * 16 + lr) * 64 + slot);
    #pragma unroll
    for (int ni = 0; ni < 2; ni++)
      bfv[ni] = *(const bf16x8*)(BsB + (wn * 32 + ni * 16 + lr) * 64 + slot);
    #pragma unroll
    for (int mi = 0; mi < 2; mi++)
      #pragma unroll
      for (int ni = 0; ni < 2; ni++)
        acc[mi][ni] = __builtin_amdgcn_mfma_f32_16x16x32_bf16(af[mi], bfv[ni], acc[mi][ni], 0, 0, 0);
    __syncthreads();
  }

  #pragma unroll
  for (int mi = 0; mi < 2; mi++) {
    #pragma unroll
    for (int ni = 0; ni < 2; ni++) {
      const int row0 = bm * 64 + wm * 32 + mi * 16 + lk * 4;
      const int col  = bn * 64 + wn * 32 + ni * 16 + lr;
      if (EPI == 2) {
        #pragma unroll
        for (int r = 0; r < 4; r++)
          g.outB[(size_t)(row0 + r) * g.ldB + col] = f2b(acc[mi][ni][r]);
      } else if (EPI == 3) {
        #pragma unroll
        for (int r = 0; r < 4; r++)
          g.outBT[(size_t)col * 512 + (row0 + r)] = f2b(acc[mi][ni][r]);
      } else if (EPI == 4) {
        #pragma unroll
        for (int r = 0; r < 4; r++) {
          int row = row0 + r;
          float d = 2.f * b2f(g.Yprev[row * 512 + col]) - acc[mi][ni][r];
          g.outB[(size_t)row * 512 + col] = f2b(d);
        }
      }
    }
  }
}

template<int EPI>
__global__ __launch_bounds__(256) void gemm64(GemmArgs g)
{
  __shared__ __align__(16) u16 As[64 * 32];
  __shared__ __align__(16) u16 Bs[64 * 32];
  gemm64_body<EPI>(g, blockIdx.y, blockIdx.x, As, Bs);
}

// ---------------------------------------------------------------------------
// fused: blocks 0..127 = tanh recurrence; blocks 128..191 = gemm64<3> (T0T)
// Solve: 4 waves x 16 rows; lane (r,g): batchrow=r, statecols g*4+e per tile.
// Per 32-superblock: 2x [LDS transpose-gather -> redundant 16-step scalar
// triangular solve (pure VALU chain)], rect 16->16 via zero-padded MFMA,
// trailing tiles via full K=32 MFMA. B-fragments and P-stores lane-local.
// ---------------------------------------------------------------------------
__global__ __launch_bounds__(256) void k_solve_a(
    const float* __restrict__ base2, const u16* __restrict__ Ddg2,
    const float* __restrict__ Dt16, u16* __restrict__ P, GemmArgs ga)
{
  __shared__ __align__(16) char DdL[2][16384];
  __shared__ __align__(16) float DtL[4096];
  __shared__ __align__(16) float tb[4][16][40];

  if (blockIdx.x >= 128) {
    int q = blockIdx.x - 128;
    gemm64_body<3>(ga, q >> 3, q & 7, (u16*)&DdL[0][0], (u16*)&DdL[0][8192]);
    return;
  }

  const int tid = threadIdx.x, l = tid & 63, w = tid >> 6;
  const int r = l & 15, g = l >> 4;
  const int row = blockIdx.x * 64 + w * 16 + r;

  const char* DtG = (const char*)Dt16;
  #pragma unroll
  for (int i = 0; i < 4; i++)
    gl16(DtG + i * 4096 + tid * 16, (char*)DtL + i * 4096 + tid * 16);
  const char* DgG = (const char*)Ddg2;
  #pragma unroll
  for (int i = 0; i < 4; i++)
    gl16(DgG + i * 4096 + tid * 16, DdL[0] + i * 4096 + tid * 16);

  f32x4 st[16];
  const float* bp = base2 + (size_t)row * 256 + g * 4;
  #pragma unroll
  for (int t = 0; t < 16; t++) st[t] = *(const f32x4*)(bp + t * 16);

  u32x4 pkA[8];
  float* tbr = &tb[w][r][0];
  __syncthreads();

  #pragma unroll
  for (int sb = 0; sb < 8; sb++) {
    if (sb < 7) {
      #pragma unroll
      for (int i = 0; i < 4; i++)
        gl16(DgG + (sb + 1) * 16384 + i * 4096 + tid * 16,
             DdL[(sb + 1) & 1] + i * 4096 + tid * 16);
    }
    float ws[8];
    #pragma unroll
    for (int i = 0; i < 8; i++) ws[i] = 0.f;
    f32x4 vv[4];

    // ---- lo 16-tile: gather, solve
    *(f32x4*)(tbr + g * 4) = st[2 * sb];
    vv[0] = *(const f32x4*)(tbr);      vv[1] = *(const f32x4*)(tbr + 4);
    vv[2] = *(const f32x4*)(tbr + 8);  vv[3] = *(const f32x4*)(tbr + 12);
    {
      const float* dt = DtL + (2 * sb) * 256;
      #pragma unroll
      for (int k2 = 0; k2 < 16; k2++) {
        float v = vv[k2 >> 2][k2 & 3];
        float ex = __expf(2.f * v);
        float wv = 1.f - 2.f * __fdividef(1.f, ex + 1.f);
        if (g == (k2 >> 3)) ws[k2 & 7] = wv;
        #pragma unroll
        for (int j = k2 >> 2; j < 4; j++)
          vv[j] += wv * *(const f32x4*)(dt + k2 * 16 + j * 4);
      }
    }
    // rect 16->16 MFMA (B zero-padded for k>=16: lanes g>=2 have ws=0)
    {
      u32x4 pk;
      pk.x = (u32)f2b(ws[0]) | ((u32)f2b(ws[1]) << 16);
      pk.y = (u32)f2b(ws[2]) | ((u32)f2b(ws[3]) << 16);
      pk.z = (u32)f2b(ws[4]) | ((u32)f2b(ws[5]) << 16);
      pk.w = (u32)f2b(ws[6]) | ((u32)f2b(ws[7]) << 16);
      union { u32x4 uu; bf16x8 bb; } cv; cv.uu = pk;
      bf16x8 Af = *(const bf16x8*)(DdL[sb & 1] + (2 * sb + 1) * 1024 + l * 16);
      st[2 * sb + 1] = __builtin_amdgcn_mfma_f32_16x16x32_bf16(Af, cv.bb, st[2 * sb + 1], 0, 0, 0);
    }
    // ---- hi 16-tile: gather, solve
    *(f32x4*)(tbr + g * 4) = st[2 * sb + 1];
    vv[0] = *(const f32x4*)(tbr);      vv[1] = *(const f32x4*)(tbr + 4);
    vv[2] = *(const f32x4*)(tbr + 8);  vv[3] = *(const f32x4*)(tbr + 12);
    {
      const float* dt = DtL + (2 * sb + 1) * 256;
      #pragma unroll
      for (int k2 = 0; k2 < 16; k2++) {
        float v = vv[k2 >> 2][k2 & 3];
        float ex = __expf(2.f * v);
        float wv = 1.f - 2.f * __fdividef(1.f, ex + 1.f);
        if (g == 2 + (k2 >> 3)) ws[k2 & 7] = wv;
        #pragma unroll
        for (int j = k2 >> 2; j < 4; j++)
          vv[j] += wv * *(const f32x4*)(dt + k2 * 16 + j * 4);
      }
    }
    // full B fragment, trailing tiles
    {
      u32x4 pk;
      pk.x = (u32)f2b(ws[0]) | ((u32)f2b(ws[1]) << 16);
      pk.y = (u32)f2b(ws[2]) | ((u32)f2b(ws[3]) << 16);
      pk.z = (u32)f2b(ws[4]) | ((u32)f2b(ws[5]) << 16);
      pk.w = (u32)f2b(ws[6]) | ((u32)f2b(ws[7]) << 16);
      pkA[sb] = pk;
      union { u32x4 uu; bf16x8 bb; } cv; cv.uu = pk;
      #pragma unroll
      for (int t = 0; t < 16; t++) {
        if (t >= 2 * sb + 2) {
          bf16x8 Af = *(const bf16x8*)(DdL[sb & 1] + t * 1024 + l * 16);
          st[t] = __builtin_amdgcn_mfma_f32_16x16x32_bf16(Af, cv.bb, st[t], 0, 0, 0);
        }
      }
    }
    __syncthreads();
  }

  u16* Pr = P + (size_t)row * 896 + 512;
  #pragma unroll
  for (int sb = 0; sb < 8; sb++)
    *(u32x4*)(Pr + sb * 32 + g * 8) = pkA[sb];
}

// ---------------------------------------------------------------------------
extern "C" void kernel_launch(void* const* d_in, const int* in_sizes, int n_in,
                              void* d_out, int out_size, void* d_ws, size_t ws_size,
                              hipStream_t stream)
{
  const float* x   = (const float*)d_in[0];
  const float* u   = (const float*)d_in[1];
  const float* C1  = (const float*)d_in[2];
  const float* D11 = (const float*)d_in[3];
  const float* D12 = (const float*)d_in[4];
  const float* Lam = (const float*)d_in[5];
  const float* bv  = (const float*)d_in[6];
  const float* E   = (const float*)d_in[7];
  const float* F   = (const float*)d_in[8];
  const float* B1  = (const float*)d_in[9];
  const float* B2  = (const float*)d_in[10];
  const float* C2  = (const float*)d_in[11];
  const float* D21 = (const float*)d_in[12];

  char* ws = (char*)d_ws;
  u16*   P      = (u16*)(ws);                 // 14,680,064
  u16*   Qt     = (u16*)(ws + 14680064);      //  1,146,880
  u16*   Rt     = (u16*)(ws + 15826944);      //    458,752
  float* base2  = (float*)(ws + 16285696);    //  8,388,608
  u16*   Ddg2   = (u16*)(ws + 24674304);      //    131,072
  float* Dt16   = (float*)(ws + 24805376);    //     16,384
  u16*   Ebf    = (u16*)(ws + 24838144);      //    524,288
  u16*   Y0     = (u16*)(ws + 25362432);
  u16*   Z0     = (u16*)(ws + 25886720);
  u16*   T0T    = (u16*)(ws + 26411008);
  u16*   Y1     = (u16*)(ws + 26935296);
  u16*   McatT  = (u16*)(ws + 27459584);      //    917,504
  float* invLam = (float*)(ws + 28377088);

  float* dxOut = (float*)d_out;
  float* yOut  = dxOut + (size_t)8192 * 512;

  k_prepc<<<8465, 256, 0, stream>>>(x, u, C1, D11, D12, Lam, E, F, B1, B2, C2, D21,
                                    Ebf, Y0, Z0, McatT, Qt, Rt, invLam, Ddg2, Dt16, P);

  GemmArgs bb{}; bb.A = P; bb.B = Rt; bb.K = 896; bb.outF = base2;
  bb.bv = bv; bb.iLam = invLam;
  gemm_nt<0><<<dim3(2, 64), 256, 0, stream>>>(bb);           // base2

  GemmArgs a{}; a.A = Ebf; a.B = Z0; a.K = 512; a.outBT = T0T;
  k_solve_a<<<192, 256, 0, stream>>>(base2, Ddg2, Dt16, P, a); // w + T0T

  GemmArgs b{}; b.A = Y0; b.B = T0T; b.K = 512; b.outB = Y1; b.ldB = 512;
  b.Yprev = Y0;
  gemm64<4><<<dim3(8, 8), 256, 0, stream>>>(b);              // Y1 = 2Y0 - Y0@(E@Y0)

  GemmArgs qq{}; qq.A = Y1; qq.B = McatT; qq.K = 512; qq.outB = Qt; qq.ldB = 896;
  gemm64<2><<<dim3(14, 8), 256, 0, stream>>>(qq);            // Qt[0:512] = Einv@[F B1 B2]

  GemmArgs ff{}; ff.A = P; ff.B = Qt; ff.K = 896; ff.dxOut = dxOut; ff.yOut = yOut;
  gemm_nt<1><<<dim3(5, 64), 256, 0, stream>>>(ff);           // [dx | y]
  (void)in_sizes; (void)n_in; (void)out_size; (void)ws_size;
}

// Round 7
// 98.400 us; speedup vs baseline: 1.6567x; 1.2244x over previous
//
#include <hip/hip_runtime.h>

typedef unsigned short u16;
typedef unsigned int   u32;
typedef __attribute__((ext_vector_type(8))) __bf16 bf16x8;
typedef __attribute__((ext_vector_type(4))) float  f32x4;
typedef __attribute__((ext_vector_type(4))) u16    u16x4;
typedef __attribute__((ext_vector_type(4))) u32    u32x4;

#define DEV __device__ __forceinline__

DEV u16 f2b(float f){ union{float f;u32 u;}a; a.f=f; u32 r=a.u + 0x7FFFu + ((a.u>>16)&1u); return (u16)(r>>16); }
DEV float b2f(u16 h){ union{u32 u;float f;}a; a.u=((u32)h)<<16; return a.f; }

typedef __attribute__((address_space(1))) void* gp1;
typedef __attribute__((address_space(3))) void* lp3;
DEV void gl16(const void* g, void* l){
  __builtin_amdgcn_global_load_lds((gp1)g, (lp3)l, 16, 0, 0);
}

// ---------------------------------------------------------------------------
// fused prep: transposes (blocks 0..703) + elementwise prep (rest)
// P layout: [x (0-511) | u (512-639) | w (640-895)]
// McatT rows: [F^T (0-511) | B2^T (512-639) | B1^T (640-895)], each 512 wide
// Rt: 256 x 640 = [C1 | D12]
// Qt y-rows (512-639): [C2 | 0 (128) | D21]
// Ddg2: MFMA-A fragment layout [(sb*16+t)*64+l]*8+j = D~[t*16+(l&15)][sb*32+(l>>4)*8+j]
// Dt16: [T][k2][n2] f32 = D~[T*16+n2][T*16+k2] if n2>k2 else 0
// ---------------------------------------------------------------------------
__global__ __launch_bounds__(256) void k_prepc(
    const float* __restrict__ x,  const float* __restrict__ u,
    const float* __restrict__ C1, const float* __restrict__ D11,
    const float* __restrict__ D12, const float* __restrict__ Lam,
    const float* __restrict__ E,  const float* __restrict__ F,
    const float* __restrict__ B1, const float* __restrict__ B2,
    const float* __restrict__ C2, const float* __restrict__ D21,
    u16* Ebf, u16* Y0, u16* Z0, u16* McatT, u16* Qt, u16* Rt,
    float* invLam, u16* Ddg2, float* Dt16, u16* P)
{
  if (blockIdx.x < 704) {                   // tiled transposes
    __shared__ float t[32][33];
    int bid = blockIdx.x;
    const int tx = threadIdx.x & 31, ty = threadIdx.x >> 5;
    const float* src; u16* dst; int srcC, nA, task;
    if (bid < 256)      { task = 0; src = E;   srcC = 512; dst = Z0;    nA = 16; }
    else if (bid < 512) { task = 1; src = F;   srcC = 512; dst = McatT; nA = 16; bid -= 256; }
    else if (bid < 640) { task = 2; src = B1;  srcC = 256; dst = McatT + (size_t)640 * 512; nA = 8;  bid -= 512; }
    else                { task = 3; src = B2;  srcC = 128; dst = McatT + (size_t)512 * 512; nA = 4;  bid -= 640; }
    const int a0 = (bid % nA) * 32;
    const int b0 = (bid / nA) * 32;
    #pragma unroll
    for (int k = 0; k < 4; k++) {
      int srow = b0 + ty + 8 * k;
      t[ty + 8 * k][tx] = src[(size_t)srow * srcC + a0 + tx];
    }
    __syncthreads();
    #pragma unroll
    for (int k = 0; k < 4; k++) {
      int drow = a0 + ty + 8 * k, dcol = b0 + tx;
      float v = t[tx][ty + 8 * k];
      if (task == 0) v = ((drow == dcol) ? 2.f : 0.f) - v;
      dst[(size_t)drow * 512 + dcol] = f2b(v);
    }
    return;
  }
  int idx = (blockIdx.x - 704) * 256 + threadIdx.x;
  if (idx < 262144) {                       // Ebf, Y0 = 2I-E
    int i = idx >> 9, j = idx & 511;
    float e = E[idx];
    Ebf[idx] = f2b(e);
    float dij = (i == j) ? 2.f : 0.f;
    Y0[idx] = f2b(dij - e);
    return;
  }
  idx -= 262144;
  if (idx < 114688) {                       // Qt rows 512..639 (y part)
    int j = idx / 896, k = idx - j * 896;
    float v = (k < 512) ? C2[j * 512 + k]
              : (k < 640 ? 0.f : D21[j * 256 + (k - 640)]);
    Qt[(size_t)(512 + j) * 896 + k] = f2b(v);
    return;
  }
  idx -= 114688;
  if (idx < 163840) {                       // Rt (256x640): [C1 | D12]
    int n = idx / 640, k = idx - n * 640;
    float v = (k < 512) ? C1[n * 512 + k] : D12[n * 128 + (k - 512)];
    Rt[idx] = f2b(v);
    return;
  }
  idx -= 163840;
  if (idx < 256) { invLam[idx] = 1.f / Lam[idx * 257]; return; }
  idx -= 256;
  if (idx < 65536) {                        // Ddg2 fragment layout
    int sb = idx >> 13, t = (idx >> 9) & 15, l = (idx >> 3) & 63, j = idx & 7;
    int r = l & 15, g = l >> 4;
    int n = t * 16 + r, k = sb * 32 + g * 8 + j;
    Ddg2[idx] = f2b(D11[n * 256 + k] * (1.f / Lam[n * 257]));
    return;
  }
  idx -= 65536;
  if (idx < 4096) {                         // Dt16 triangular diag blocks
    int T = idx >> 8, k2 = (idx >> 4) & 15, n2 = idx & 15;
    float v = 0.f;
    if (n2 > k2) {
      int n = T * 16 + n2;
      v = D11[n * 256 + T * 16 + k2] * (1.f / Lam[n * 257]);
    }
    Dt16[idx] = v;
    return;
  }
  idx -= 4096;
  {                                         // P = [x | u | .] bf16
    int b = idx / 160, t = idx - b * 160;
    f32x4 s; u16* dst;
    if (t < 128) { s = *(const f32x4*)(x + (size_t)b * 512 + t * 4); dst = P + (size_t)b * 896 + t * 4; }
    else         { s = *(const f32x4*)(u + (size_t)b * 128 + (t - 128) * 4); dst = P + (size_t)b * 896 + 512 + (t - 128) * 4; }
    u16x4 o; o.x = f2b(s.x); o.y = f2b(s.y); o.z = f2b(s.z); o.w = f2b(s.w);
    *(u16x4*)dst = o;
  }
}

struct GemmArgs {
  const u16* A; const u16* B; int K; int lda; int ldb;
  u16* outB; int ldB;
  u16* outBT;
  const u16* Yprev;
};

// ---------------------------------------------------------------------------
// base2 GEMM: 64x128 tile, K=640; out f32 ld=256, epilogue (acc+bv)*invLam
// grid 256 blocks (bijective XCD swizzle); 2x2 waves of 32x64
// ---------------------------------------------------------------------------
__global__ __launch_bounds__(256) void gemm_b2(
    const u16* __restrict__ A, const u16* __restrict__ B, float* __restrict__ outF,
    const float* __restrict__ bv, const float* __restrict__ iLam)
{
  __shared__ __align__(16) u16 As[64 * 32];
  __shared__ __align__(16) u16 Bs[128 * 32];
  const int bid = blockIdx.x;
  const int wg = (bid & 7) * 32 + (bid >> 3);
  const int bm = wg >> 1, bn = wg & 1;
  const int tid = threadIdx.x;
  const int l = tid & 63, w = tid >> 6;
  const size_t rowbA = 896 * 2, rowbB = 640 * 2;
  const char* Ab = (const char*)A + (size_t)bm * 64 * rowbA;
  const char* Bb = (const char*)B + (size_t)bn * 128 * rowbB;
  const int o = tid * 16, o2 = o + 4096;
  const int rA = o >> 6;
  const int csA = (((o >> 4) ^ rA) & 3) << 4;
  const int rB2 = o2 >> 6;
  const int csB2 = (((o2 >> 4) ^ rB2) & 3) << 4;
  char* AsB = (char*)As; char* BsB = (char*)Bs;
  const int wm = w >> 1, wn = w & 1;
  const int lr = l & 15, lk = l >> 4;
  const int slot = ((lk ^ lr) & 3) << 4;

  f32x4 acc[2][4];
  const f32x4 zz = {0.f, 0.f, 0.f, 0.f};
  #pragma unroll
  for (int i = 0; i < 2; i++)
    #pragma unroll
    for (int j = 0; j < 4; j++) acc[i][j] = zz;

  for (int k0 = 0; k0 < 640; k0 += 32) {
    gl16(Ab + (size_t)rA * rowbA + k0 * 2 + csA, AsB + o);
    gl16(Bb + (size_t)rA * rowbB + k0 * 2 + csA, BsB + o);
    gl16(Bb + (size_t)rB2 * rowbB + k0 * 2 + csB2, BsB + o2);
    __syncthreads();
    bf16x8 af[2], bfv[4];
    #pragma unroll
    for (int mi = 0; mi < 2; mi++)
      af[mi] = *(const bf16x8*)(AsB + (wm * 32 + mi * 16 + lr) * 64 + slot);
    #pragma unroll
    for (int ni = 0; ni < 4; ni++)
      bfv[ni] = *(const bf16x8*)(BsB + (wn * 64 + ni * 16 + lr) * 64 + slot);
    #pragma unroll
    for (int mi = 0; mi < 2; mi++)
      #pragma unroll
      for (int ni = 0; ni < 4; ni++)
        acc[mi][ni] = __builtin_amdgcn_mfma_f32_16x16x32_bf16(af[mi], bfv[ni], acc[mi][ni], 0, 0, 0);
    __syncthreads();
  }

  #pragma unroll
  for (int mi = 0; mi < 2; mi++) {
    #pragma unroll
    for (int ni = 0; ni < 4; ni++) {
      const int row0 = bm * 64 + wm * 32 + mi * 16 + lk * 4;
      const int col  = bn * 128 + wn * 64 + ni * 16 + lr;
      const float bvc = bv[col], il = iLam[col];
      #pragma unroll
      for (int r = 0; r < 4; r++)
        outF[(size_t)(row0 + r) * 256 + col] = (acc[mi][ni][r] + bvc) * il;
    }
  }
}

// ---------------------------------------------------------------------------
// final GEMM: 128x64 tile, K=896; writes dx (cols<512) / y; grid 640 swizzled
// ---------------------------------------------------------------------------
__global__ __launch_bounds__(256) void gemm_f(
    const u16* __restrict__ A, const u16* __restrict__ B,
    float* __restrict__ dxOut, float* __restrict__ yOut)
{
  __shared__ __align__(16) u16 As[128 * 32];
  __shared__ __align__(16) u16 Bs[64 * 32];
  const int bid = blockIdx.x;
  const int wg = (bid & 7) * 80 + (bid >> 3);
  const int bm = wg / 10, bn = wg - bm * 10;
  const int tid = threadIdx.x;
  const int l = tid & 63, w = tid >> 6;
  const size_t rowb = 896 * 2;
  const char* Ab = (const char*)A + (size_t)bm * 128 * rowb;
  const char* Bb = (const char*)B + (size_t)bn * 64 * rowb;
  const int o = tid * 16, o2 = o + 4096;
  const int r1 = o >> 6, r2 = o2 >> 6;
  const int c1 = (((o >> 4) ^ r1) & 3) << 4;
  const int c2 = (((o2 >> 4) ^ r2) & 3) << 4;
  char* AsB = (char*)As; char* BsB = (char*)Bs;
  const int wm = w >> 1, wn = w & 1;
  const int lr = l & 15, lk = l >> 4;
  const int slot = ((lk ^ lr) & 3) << 4;

  f32x4 acc[4][2];
  const f32x4 zz = {0.f, 0.f, 0.f, 0.f};
  #pragma unroll
  for (int i = 0; i < 4; i++)
    #pragma unroll
    for (int j = 0; j < 2; j++) acc[i][j] = zz;

  for (int k0 = 0; k0 < 896; k0 += 32) {
    gl16(Ab + (size_t)r1 * rowb + k0 * 2 + c1, AsB + o);
    gl16(Ab + (size_t)r2 * rowb + k0 * 2 + c2, AsB + o2);
    gl16(Bb + (size_t)r1 * rowb + k0 * 2 + c1, BsB + o);
    __syncthreads();
    bf16x8 af[4], bfv[2];
    #pragma unroll
    for (int mi = 0; mi < 4; mi++)
      af[mi] = *(const bf16x8*)(AsB + (wm * 64 + mi * 16 + lr) * 64 + slot);
    #pragma unroll
    for (int ni = 0; ni < 2; ni++)
      bfv[ni] = *(const bf16x8*)(BsB + (wn * 32 + ni * 16 + lr) * 64 + slot);
    #pragma unroll
    for (int mi = 0; mi < 4; mi++)
      #pragma unroll
      for (int ni = 0; ni < 2; ni++)
        acc[mi][ni] = __builtin_amdgcn_mfma_f32_16x16x32_bf16(af[mi], bfv[ni], acc[mi][ni], 0, 0, 0);
    __syncthreads();
  }

  #pragma unroll
  for (int mi = 0; mi < 4; mi++) {
    #pragma unroll
    for (int ni = 0; ni < 2; ni++) {
      const int row0 = bm * 128 + wm * 64 + mi * 16 + lk * 4;
      const int col  = bn * 64 + wn * 32 + ni * 16 + lr;
      #pragma unroll
      for (int r = 0; r < 4; r++) {
        float v = acc[mi][ni][r];
        if (col < 512) dxOut[(size_t)(row0 + r) * 512 + col] = v;
        else           yOut[(size_t)(row0 + r) * 128 + (col - 512)] = v;
      }
    }
  }
}

// ---------------------------------------------------------------------------
// NT bf16 MFMA GEMM, 64x64 tile (device body + kernel) for the 512-chain
// ---------------------------------------------------------------------------
template<int EPI>
DEV void gemm64_body(const GemmArgs& g, int bm, int bn, u16* As, u16* Bs)
{
  const int tid = threadIdx.x;
  const int l = tid & 63, w = tid >> 6;
  const int K = g.K;
  const size_t rowbA = (size_t)g.lda * 2, rowbB = (size_t)g.ldb * 2;
  const char* Ab = (const char*)g.A + (size_t)bm * 64 * rowbA;
  const char* Bb = (const char*)g.B + (size_t)bn * 64 * rowbB;
  const int o = tid * 16;
  const int r0 = o >> 6;
  const int cs = (((o >> 4) ^ r0) & 3) << 4;
  char* AsB = (char*)As; char* BsB = (char*)Bs;
  const int wm = w >> 1, wn = w & 1;
  const int lr = l & 15, lk = l >> 4;
  const int slot = ((lk ^ lr) & 3) << 4;

  f32x4 acc[2][2];
  const f32x4 zz = {0.f, 0.f, 0.f, 0.f};
  acc[0][0] = zz; acc[0][1] = zz; acc[1][0] = zz; acc[1][1] = zz;

  for (int k0 = 0; k0 < K; k0 += 32) {
    gl16(Ab + (size_t)r0 * rowbA + k0 * 2 + cs, AsB + o);
    gl16(Bb + (size_t)r0 * rowbB + k0 * 2 + cs, BsB + o);
    __syncthreads();
    bf16x8 af[2], bfv[2];
    #pragma unroll
    for (int mi = 0; mi < 2; mi++)
      af[mi] = *(const bf16x8*)(AsB + (wm * 32 + mi * 16 + lr) * 64 + slot);
    #pragma unroll
    for (int ni = 0; ni < 2; ni++)
      bfv[ni] = *(const bf16x8*)(BsB + (wn * 32 + ni * 16 + lr) * 64 + slot);
    #pragma unroll
    for (int mi = 0; mi < 2; mi++)
      #pragma unroll
      for (int ni = 0; ni < 2; ni++)
        acc[mi][ni] = __builtin_amdgcn_mfma_f32_16x16x32_bf16(af[mi], bfv[ni], acc[mi][ni], 0, 0, 0);
    __syncthreads();
  }

  #pragma unroll
  for (int mi = 0; mi < 2; mi++) {
    #pragma unroll
    for (int ni = 0; ni < 2; ni++) {
      const int row0 = bm * 64 + wm * 32 + mi * 16 + lk * 4;
      const int col  = bn * 64 + wn * 32 + ni * 16 + lr;
      if (EPI == 2) {
        #pragma unroll
        for (int r = 0; r < 4; r++)
          g.outB[(size_t)(row0 + r) * g.ldB + col] = f2b(acc[mi][ni][r]);
      } else if (EPI == 3) {
        #pragma unroll
        for (int r = 0; r < 4; r++)
          g.outBT[(size_t)col * 512 + (row0 + r)] = f2b(acc[mi][ni][r]);
      } else if (EPI == 4) {
        #pragma unroll
        for (int r = 0; r < 4; r++) {
          int row = row0 + r;
          float d = 2.f * b2f(g.Yprev[row * 512 + col]) - acc[mi][ni][r];
          g.outB[(size_t)row * 512 + col] = f2b(d);
        }
      }
    }
  }
}

template<int EPI>
__global__ __launch_bounds__(256) void gemm64(GemmArgs g)
{
  __shared__ __align__(16) u16 As[64 * 32];
  __shared__ __align__(16) u16 Bs[64 * 32];
  gemm64_body<EPI>(g, blockIdx.y, blockIdx.x, As, Bs);
}

// ---------------------------------------------------------------------------
// fused: blocks 0..127 = tanh recurrence; blocks 128..191 = gemm64<3> (T0T)
// ---------------------------------------------------------------------------
__global__ __launch_bounds__(256) void k_solve_a(
    const float* __restrict__ base2, const u16* __restrict__ Ddg2,
    const float* __restrict__ Dt16, u16* __restrict__ P, GemmArgs ga)
{
  __shared__ __align__(16) char DdL[2][16384];
  __shared__ __align__(16) float DtL[4096];
  __shared__ __align__(16) float tb[4][16][40];

  if (blockIdx.x >= 128) {
    int q = blockIdx.x - 128;
    gemm64_body<3>(ga, q >> 3, q & 7, (u16*)&DdL[0][0], (u16*)&DdL[0][8192]);
    return;
  }

  const int tid = threadIdx.x, l = tid & 63, w = tid >> 6;
  const int r = l & 15, g = l >> 4;
  const int row = blockIdx.x * 64 + w * 16 + r;

  const char* DtG = (const char*)Dt16;
  #pragma unroll
  for (int i = 0; i < 4; i++)
    gl16(DtG + i * 4096 + tid * 16, (char*)DtL + i * 4096 + tid * 16);
  const char* DgG = (const char*)Ddg2;
  #pragma unroll
  for (int i = 0; i < 4; i++)
    gl16(DgG + i * 4096 + tid * 16, DdL[0] + i * 4096 + tid * 16);

  f32x4 st[16];
  const float* bp = base2 + (size_t)row * 256 + g * 4;
  #pragma unroll
  for (int t = 0; t < 16; t++) st[t] = *(const f32x4*)(bp + t * 16);

  u32x4 pkA[8];
  float* tbr = &tb[w][r][0];
  __syncthreads();

  #pragma unroll
  for (int sb = 0; sb < 8; sb++) {
    if (sb < 7) {
      #pragma unroll
      for (int i = 0; i < 4; i++)
        gl16(DgG + (sb + 1) * 16384 + i * 4096 + tid * 16,
             DdL[(sb + 1) & 1] + i * 4096 + tid * 16);
    }
    float ws[8];
    #pragma unroll
    for (int i = 0; i < 8; i++) ws[i] = 0.f;
    f32x4 vv[4];

    // ---- lo 16-tile
    *(f32x4*)(tbr + g * 4) = st[2 * sb];
    vv[0] = *(const f32x4*)(tbr);      vv[1] = *(const f32x4*)(tbr + 4);
    vv[2] = *(const f32x4*)(tbr + 8);  vv[3] = *(const f32x4*)(tbr + 12);
    {
      const float* dt = DtL + (2 * sb) * 256;
      #pragma unroll
      for (int k2 = 0; k2 < 16; k2++) {
        float v = vv[k2 >> 2][k2 & 3];
        float ex = __expf(2.f * v);
        float wv = 1.f - 2.f * __fdividef(1.f, ex + 1.f);
        if (g == (k2 >> 3)) ws[k2 & 7] = wv;
        #pragma unroll
        for (int j = k2 >> 2; j < 4; j++)
          vv[j] += wv * *(const f32x4*)(dt + k2 * 16 + j * 4);
      }
    }
    {
      u32x4 pk;
      pk.x = (u32)f2b(ws[0]) | ((u32)f2b(ws[1]) << 16);
      pk.y = (u32)f2b(ws[2]) | ((u32)f2b(ws[3]) << 16);
      pk.z = (u32)f2b(ws[4]) | ((u32)f2b(ws[5]) << 16);
      pk.w = (u32)f2b(ws[6]) | ((u32)f2b(ws[7]) << 16);
      union { u32x4 uu; bf16x8 bb; } cv; cv.uu = pk;
      bf16x8 Af = *(const bf16x8*)(DdL[sb & 1] + (2 * sb + 1) * 1024 + l * 16);
      st[2 * sb + 1] = __builtin_amdgcn_mfma_f32_16x16x32_bf16(Af, cv.bb, st[2 * sb + 1], 0, 0, 0);
    }
    // ---- hi 16-tile
    *(f32x4*)(tbr + g * 4) = st[2 * sb + 1];
    vv[0] = *(const f32x4*)(tbr);      vv[1] = *(const f32x4*)(tbr + 4);
    vv[2] = *(const f32x4*)(tbr + 8);  vv[3] = *(const f32x4*)(tbr + 12);
    {
      const float* dt = DtL + (2 * sb + 1) * 256;
      #pragma unroll
      for (int k2 = 0; k2 < 16; k2++) {
        float v = vv[k2 >> 2][k2 & 3];
        float ex = __expf(2.f * v);
        float wv = 1.f - 2.f * __fdividef(1.f, ex + 1.f);
        if (g == 2 + (k2 >> 3)) ws[k2 & 7] = wv;
        #pragma unroll
        for (int j = k2 >> 2; j < 4; j++)
          vv[j] += wv * *(const f32x4*)(dt + k2 * 16 + j * 4);
      }
    }
    {
      u32x4 pk;
      pk.x = (u32)f2b(ws[0]) | ((u32)f2b(ws[1]) << 16);
      pk.y = (u32)f2b(ws[2]) | ((u32)f2b(ws[3]) << 16);
      pk.z = (u32)f2b(ws[4]) | ((u32)f2b(ws[5]) << 16);
      pk.w = (u32)f2b(ws[6]) | ((u32)f2b(ws[7]) << 16);
      pkA[sb] = pk;
      union { u32x4 uu; bf16x8 bb; } cv; cv.uu = pk;
      #pragma unroll
      for (int t = 0; t < 16; t++) {
        if (t >= 2 * sb + 2) {
          bf16x8 Af = *(const bf16x8*)(DdL[sb & 1] + t * 1024 + l * 16);
          st[t] = __builtin_amdgcn_mfma_f32_16x16x32_bf16(Af, cv.bb, st[t], 0, 0, 0);
        }
      }
    }
    __syncthreads();
  }

  u16* Pr = P + (size_t)row * 896 + 640;
  #pragma unroll
  for (int sb = 0; sb < 8; sb++)
    *(u32x4*)(Pr + sb * 32 + g * 8) = pkA[sb];
}

// ---------------------------------------------------------------------------
extern "C" void kernel_launch(void* const* d_in, const int* in_sizes, int n_in,
                              void* d_out, int out_size, void* d_ws, size_t ws_size,
                              hipStream_t stream)
{
  const float* x   = (const float*)d_in[0];
  const float* u   = (const float*)d_in[1];
  const float* C1  = (const float*)d_in[2];
  const float* D11 = (const float*)d_in[3];
  const float* D12 = (const float*)d_in[4];
  const float* Lam = (const float*)d_in[5];
  const float* bv  = (const float*)d_in[6];
  const float* E   = (const float*)d_in[7];
  const float* F   = (const float*)d_in[8];
  const float* B1  = (const float*)d_in[9];
  const float* B2  = (const float*)d_in[10];
  const float* C2  = (const float*)d_in[11];
  const float* D21 = (const float*)d_in[12];

  char* ws = (char*)d_ws;
  u16*   P      = (u16*)(ws);                 // 14,680,064
  u16*   Qt     = (u16*)(ws + 14680064);      //  1,146,880
  u16*   Rt     = (u16*)(ws + 15826944);      //    327,680
  float* base2  = (float*)(ws + 16285696);    //  8,388,608
  u16*   Ddg2   = (u16*)(ws + 24674304);      //    131,072
  float* Dt16   = (float*)(ws + 24805376);    //     16,384
  u16*   Ebf    = (u16*)(ws + 24838144);      //    524,288
  u16*   Y0     = (u16*)(ws + 25362432);
  u16*   Z0     = (u16*)(ws + 25886720);
  u16*   T0T    = (u16*)(ws + 26411008);
  u16*   Y1     = (u16*)(ws + 26935296);
  u16*   McatT  = (u16*)(ws + 27459584);      //    917,504
  float* invLam = (float*)(ws + 28377088);

  float* dxOut = (float*)d_out;
  float* yOut  = dxOut + (size_t)8192 * 512;

  k_prepc<<<8209, 256, 0, stream>>>(x, u, C1, D11, D12, Lam, E, F, B1, B2, C2, D21,
                                    Ebf, Y0, Z0, McatT, Qt, Rt, invLam, Ddg2, Dt16, P);

  gemm_b2<<<256, 256, 0, stream>>>(P, Rt, base2, bv, invLam);        // base2 (K=640)

  GemmArgs a{}; a.A = Ebf; a.B = Z0; a.K = 512; a.lda = 512; a.ldb = 512; a.outBT = T0T;
  k_solve_a<<<192, 256, 0, stream>>>(base2, Ddg2, Dt16, P, a);       // w + T0T

  GemmArgs b{}; b.A = Y0; b.B = T0T; b.K = 512; b.lda = 512; b.ldb = 512;
  b.outB = Y1; b.ldB = 512; b.Yprev = Y0;
  gemm64<4><<<dim3(8, 8), 256, 0, stream>>>(b);                      // Y1 = 2Y0 - Y0@(E@Y0)

  GemmArgs qq{}; qq.A = Y1; qq.B = McatT; qq.K = 512; qq.lda = 512; qq.ldb = 512;
  qq.outB = Qt; qq.ldB = 896;
  gemm64<2><<<dim3(14, 8), 256, 0, stream>>>(qq);                    // Qt[0:512]

  gemm_f<<<640, 256, 0, stream>>>(P, Qt, dxOut, yOut);               // [dx | y]
  (void)in_sizes; (void)n_in; (void)out_size; (void)ws_size;
}

// Round 8
// 83.955 us; speedup vs baseline: 1.9417x; 1.1721x over previous
//
#include <hip/hip_runtime.h>

typedef unsigned short u16;
typedef unsigned int   u32;
typedef __attribute__((ext_vector_type(8))) __bf16 bf16x8;
typedef __attribute__((ext_vector_type(4))) float  f32x4;
typedef __attribute__((ext_vector_type(4))) u16    u16x4;
typedef __attribute__((ext_vector_type(4))) u32    u32x4;

#define DEV __device__ __forceinline__

DEV u16 f2b(float f){ union{float f;u32 u;}a; a.f=f; u32 r=a.u + 0x7FFFu + ((a.u>>16)&1u); return (u16)(r>>16); }
DEV float b2f(u16 h){ union{u32 u;float f;}a; a.u=((u32)h)<<16; return a.f; }

typedef __attribute__((address_space(1))) void* gp1;
typedef __attribute__((address_space(3))) void* lp3;
DEV void gl16(const void* g, void* l){
  __builtin_amdgcn_global_load_lds((gp1)g, (lp3)l, 16, 0, 0);
}

// ---------------------------------------------------------------------------
// fused prep: transposes (blocks 0..703) + elementwise prep (rest)
// P: [x | u | w];  Rt: 256x640 = [C1 | D12];  Qt y-rows: [C2 | 0 | D21]
// ---------------------------------------------------------------------------
__global__ __launch_bounds__(256) void k_prepc(
    const float* __restrict__ x,  const float* __restrict__ u,
    const float* __restrict__ C1, const float* __restrict__ D11,
    const float* __restrict__ D12, const float* __restrict__ Lam,
    const float* __restrict__ E,  const float* __restrict__ F,
    const float* __restrict__ B1, const float* __restrict__ B2,
    const float* __restrict__ C2, const float* __restrict__ D21,
    u16* Ebf, u16* Y0, u16* Z0, u16* McatT, u16* Qt, u16* Rt,
    float* invLam, u16* Ddg2, float* Dt16, u16* P)
{
  if (blockIdx.x < 704) {                   // tiled transposes
    __shared__ float t[32][33];
    int bid = blockIdx.x;
    const int tx = threadIdx.x & 31, ty = threadIdx.x >> 5;
    const float* src; u16* dst; int srcC, nA, task;
    if (bid < 256)      { task = 0; src = E;   srcC = 512; dst = Z0;    nA = 16; }
    else if (bid < 512) { task = 1; src = F;   srcC = 512; dst = McatT; nA = 16; bid -= 256; }
    else if (bid < 640) { task = 2; src = B1;  srcC = 256; dst = McatT + (size_t)640 * 512; nA = 8;  bid -= 512; }
    else                { task = 3; src = B2;  srcC = 128; dst = McatT + (size_t)512 * 512; nA = 4;  bid -= 640; }
    const int a0 = (bid % nA) * 32;
    const int b0 = (bid / nA) * 32;
    #pragma unroll
    for (int k = 0; k < 4; k++) {
      int srow = b0 + ty + 8 * k;
      t[ty + 8 * k][tx] = src[(size_t)srow * srcC + a0 + tx];
    }
    __syncthreads();
    #pragma unroll
    for (int k = 0; k < 4; k++) {
      int drow = a0 + ty + 8 * k, dcol = b0 + tx;
      float v = t[tx][ty + 8 * k];
      if (task == 0) v = ((drow == dcol) ? 2.f : 0.f) - v;
      dst[(size_t)drow * 512 + dcol] = f2b(v);
    }
    return;
  }
  int idx = (blockIdx.x - 704) * 256 + threadIdx.x;
  if (idx < 262144) {                       // Ebf, Y0 = 2I-E
    int i = idx >> 9, j = idx & 511;
    float e = E[idx];
    Ebf[idx] = f2b(e);
    float dij = (i == j) ? 2.f : 0.f;
    Y0[idx] = f2b(dij - e);
    return;
  }
  idx -= 262144;
  if (idx < 114688) {                       // Qt rows 512..639 (y part)
    int j = idx / 896, k = idx - j * 896;
    float v = (k < 512) ? C2[j * 512 + k]
              : (k < 640 ? 0.f : D21[j * 256 + (k - 640)]);
    Qt[(size_t)(512 + j) * 896 + k] = f2b(v);
    return;
  }
  idx -= 114688;
  if (idx < 163840) {                       // Rt (256x640): [C1 | D12]
    int n = idx / 640, k = idx - n * 640;
    float v = (k < 512) ? C1[n * 512 + k] : D12[n * 128 + (k - 512)];
    Rt[idx] = f2b(v);
    return;
  }
  idx -= 163840;
  if (idx < 256) { invLam[idx] = 1.f / Lam[idx * 257]; return; }
  idx -= 256;
  if (idx < 65536) {                        // Ddg2 fragment layout
    int sb = idx >> 13, t = (idx >> 9) & 15, l = (idx >> 3) & 63, j = idx & 7;
    int r = l & 15, g = l >> 4;
    int n = t * 16 + r, k = sb * 32 + g * 8 + j;
    Ddg2[idx] = f2b(D11[n * 256 + k] * (1.f / Lam[n * 257]));
    return;
  }
  idx -= 65536;
  if (idx < 4096) {                         // Dt16 triangular diag blocks
    int T = idx >> 8, k2 = (idx >> 4) & 15, n2 = idx & 15;
    float v = 0.f;
    if (n2 > k2) {
      int n = T * 16 + n2;
      v = D11[n * 256 + T * 16 + k2] * (1.f / Lam[n * 257]);
    }
    Dt16[idx] = v;
    return;
  }
  idx -= 4096;
  {                                         // P = [x | u | .] bf16
    int b = idx / 160, t = idx - b * 160;
    f32x4 s; u16* dst;
    if (t < 128) { s = *(const f32x4*)(x + (size_t)b * 512 + t * 4); dst = P + (size_t)b * 896 + t * 4; }
    else         { s = *(const f32x4*)(u + (size_t)b * 128 + (t - 128) * 4); dst = P + (size_t)b * 896 + 512 + (t - 128) * 4; }
    u16x4 o; o.x = f2b(s.x); o.y = f2b(s.y); o.z = f2b(s.z); o.w = f2b(s.w);
    *(u16x4*)dst = o;
  }
}

struct GemmArgs {
  const u16* A; const u16* B; int K; int lda; int ldb;
  u16* outB; int ldB;
  u16* outBT;
  const u16* Yprev;
};

// ---------------------------------------------------------------------------
// 64x64-tile NT GEMM body, 256 threads (2x2 waves of 32x32)
// ---------------------------------------------------------------------------
template<int EPI>
DEV void gemm64_body(const GemmArgs& g, int bm, int bn, u16* As, u16* Bs)
{
  const int tid = threadIdx.x;
  const int l = tid & 63, w = tid >> 6;
  const int K = g.K;
  const size_t rowbA = (size_t)g.lda * 2, rowbB = (size_t)g.ldb * 2;
  const char* Ab = (const char*)g.A + (size_t)bm * 64 * rowbA;
  const char* Bb = (const char*)g.B + (size_t)bn * 64 * rowbB;
  const int o = tid * 16;
  const int r0 = o >> 6;
  const int cs = (((o >> 4) ^ r0) & 3) << 4;
  char* AsB = (char*)As; char* BsB = (char*)Bs;
  const int wm = w >> 1, wn = w & 1;
  const int lr = l & 15, lk = l >> 4;
  const int slot = ((lk ^ lr) & 3) << 4;

  f32x4 acc[2][2];
  const f32x4 zz = {0.f, 0.f, 0.f, 0.f};
  acc[0][0] = zz; acc[0][1] = zz; acc[1][0] = zz; acc[1][1] = zz;

  for (int k0 = 0; k0 < K; k0 += 32) {
    gl16(Ab + (size_t)r0 * rowbA + k0 * 2 + cs, AsB + o);
    gl16(Bb + (size_t)r0 * rowbB + k0 * 2 + cs, BsB + o);
    __syncthreads();
    bf16x8 af[2], bfv[2];
    #pragma unroll
    for (int mi = 0; mi < 2; mi++)
      af[mi] = *(const bf16x8*)(AsB + (wm * 32 + mi * 16 + lr) * 64 + slot);
    #pragma unroll
    for (int ni = 0; ni < 2; ni++)
      bfv[ni] = *(const bf16x8*)(BsB + (wn * 32 + ni * 16 + lr) * 64 + slot);
    #pragma unroll
    for (int mi = 0; mi < 2; mi++)
      #pragma unroll
      for (int ni = 0; ni < 2; ni++)
        acc[mi][ni] = __builtin_amdgcn_mfma_f32_16x16x32_bf16(af[mi], bfv[ni], acc[mi][ni], 0, 0, 0);
    __syncthreads();
  }

  #pragma unroll
  for (int mi = 0; mi < 2; mi++) {
    #pragma unroll
    for (int ni = 0; ni < 2; ni++) {
      const int row0 = bm * 64 + wm * 32 + mi * 16 + lk * 4;
      const int col  = bn * 64 + wn * 32 + ni * 16 + lr;
      if (EPI == 2) {
        #pragma unroll
        for (int r = 0; r < 4; r++)
          g.outB[(size_t)(row0 + r) * g.ldB + col] = f2b(acc[mi][ni][r]);
      } else if (EPI == 3) {
        #pragma unroll
        for (int r = 0; r < 4; r++)
          g.outBT[(size_t)col * 512 + (row0 + r)] = f2b(acc[mi][ni][r]);
      }
    }
  }
}

// ---------------------------------------------------------------------------
// 64x64-tile NT GEMM body, 128 threads (2 waves of 32x64) — for solve fusion
// ---------------------------------------------------------------------------
template<int EPI>
DEV void gemm64h_body(const GemmArgs& g, int bm, int bn, u16* As, u16* Bs)
{
  const int tid = threadIdx.x;
  const int l = tid & 63, w = tid >> 6;           // w in {0,1}
  const int K = g.K;
  const size_t rowbA = (size_t)g.lda * 2, rowbB = (size_t)g.ldb * 2;
  const char* Ab = (const char*)g.A + (size_t)bm * 64 * rowbA;
  const char* Bb = (const char*)g.B + (size_t)bn * 64 * rowbB;
  const int o1 = tid * 16, o2 = o1 + 2048;
  const int rA1 = o1 >> 6, rA2 = o2 >> 6;
  const int cs1 = (((o1 >> 4) ^ rA1) & 3) << 4;
  const int cs2 = (((o2 >> 4) ^ rA2) & 3) << 4;
  char* AsB = (char*)As; char* BsB = (char*)Bs;
  const int lr = l & 15, lk = l >> 4;
  const int slot = ((lk ^ lr) & 3) << 4;

  f32x4 acc[2][4];
  const f32x4 zz = {0.f, 0.f, 0.f, 0.f};
  #pragma unroll
  for (int i = 0; i < 2; i++)
    #pragma unroll
    for (int j = 0; j < 4; j++) acc[i][j] = zz;

  for (int k0 = 0; k0 < K; k0 += 32) {
    gl16(Ab + (size_t)rA1 * rowbA + k0 * 2 + cs1, AsB + o1);
    gl16(Ab + (size_t)rA2 * rowbA + k0 * 2 + cs2, AsB + o2);
    gl16(Bb + (size_t)rA1 * rowbB + k0 * 2 + cs1, BsB + o1);
    gl16(Bb + (size_t)rA2 * rowbB + k0 * 2 + cs2, BsB + o2);
    __syncthreads();
    bf16x8 af[2], bfv[4];
    #pragma unroll
    for (int mi = 0; mi < 2; mi++)
      af[mi] = *(const bf16x8*)(AsB + (w * 32 + mi * 16 + lr) * 64 + slot);
    #pragma unroll
    for (int ni = 0; ni < 4; ni++)
      bfv[ni] = *(const bf16x8*)(BsB + (ni * 16 + lr) * 64 + slot);
    #pragma unroll
    for (int mi = 0; mi < 2; mi++)
      #pragma unroll
      for (int ni = 0; ni < 4; ni++)
        acc[mi][ni] = __builtin_amdgcn_mfma_f32_16x16x32_bf16(af[mi], bfv[ni], acc[mi][ni], 0, 0, 0);
    __syncthreads();
  }

  #pragma unroll
  for (int mi = 0; mi < 2; mi++) {
    #pragma unroll
    for (int ni = 0; ni < 4; ni++) {
      const int row0 = bm * 64 + w * 32 + mi * 16 + lk * 4;
      const int col  = bn * 64 + ni * 16 + lr;
      if (EPI == 4) {
        #pragma unroll
        for (int r = 0; r < 4; r++) {
          int row = row0 + r;
          float d = 2.f * b2f(g.Yprev[row * 512 + col]) - acc[mi][ni][r];
          g.outB[(size_t)row * 512 + col] = f2b(d);
        }
      }
    }
  }
}

template<int EPI>
__global__ __launch_bounds__(256) void gemm64(GemmArgs g)
{
  __shared__ __align__(16) u16 As[64 * 32];
  __shared__ __align__(16) u16 Bs[64 * 32];
  gemm64_body<EPI>(g, blockIdx.y, blockIdx.x, As, Bs);
}

// ---------------------------------------------------------------------------
// L2: blocks 0..255 = base2 GEMM (64x128, K=640, XCD-swizzled);
//     blocks 256..319 = T0T = (E@Y0)^T via gemm64_body<3>
// ---------------------------------------------------------------------------
__global__ __launch_bounds__(256) void gemm_b2(
    const u16* __restrict__ A, const u16* __restrict__ B, float* __restrict__ outF,
    const float* __restrict__ bv, const float* __restrict__ iLam, GemmArgs ga)
{
  __shared__ __align__(16) u16 As[64 * 32];
  __shared__ __align__(16) u16 Bs[128 * 32];
  if (blockIdx.x >= 256) {
    int q = blockIdx.x - 256;
    gemm64_body<3>(ga, q >> 3, q & 7, As, Bs);
    return;
  }
  const int bid = blockIdx.x;
  const int wg = (bid & 7) * 32 + (bid >> 3);
  const int bm = wg >> 1, bn = wg & 1;
  const int tid = threadIdx.x;
  const int l = tid & 63, w = tid >> 6;
  const size_t rowbA = 896 * 2, rowbB = 640 * 2;
  const char* Ab = (const char*)A + (size_t)bm * 64 * rowbA;
  const char* Bb = (const char*)B + (size_t)bn * 128 * rowbB;
  const int o = tid * 16, o2 = o + 4096;
  const int rA = o >> 6;
  const int csA = (((o >> 4) ^ rA) & 3) << 4;
  const int rB2 = o2 >> 6;
  const int csB2 = (((o2 >> 4) ^ rB2) & 3) << 4;
  char* AsB = (char*)As; char* BsB = (char*)Bs;
  const int wm = w >> 1, wn = w & 1;
  const int lr = l & 15, lk = l >> 4;
  const int slot = ((lk ^ lr) & 3) << 4;

  f32x4 acc[2][4];
  const f32x4 zz = {0.f, 0.f, 0.f, 0.f};
  #pragma unroll
  for (int i = 0; i < 2; i++)
    #pragma unroll
    for (int j = 0; j < 4; j++) acc[i][j] = zz;

  for (int k0 = 0; k0 < 640; k0 += 32) {
    gl16(Ab + (size_t)rA * rowbA + k0 * 2 + csA, AsB + o);
    gl16(Bb + (size_t)rA * rowbB + k0 * 2 + csA, BsB + o);
    gl16(Bb + (size_t)rB2 * rowbB + k0 * 2 + csB2, BsB + o2);
    __syncthreads();
    bf16x8 af[2], bfv[4];
    #pragma unroll
    for (int mi = 0; mi < 2; mi++)
      af[mi] = *(const bf16x8*)(AsB + (wm * 32 + mi * 16 + lr) * 64 + slot);
    #pragma unroll
    for (int ni = 0; ni < 4; ni++)
      bfv[ni] = *(const bf16x8*)(BsB + (wn * 64 + ni * 16 + lr) * 64 + slot);
    #pragma unroll
    for (int mi = 0; mi < 2; mi++)
      #pragma unroll
      for (int ni = 0; ni < 4; ni++)
        acc[mi][ni] = __builtin_amdgcn_mfma_f32_16x16x32_bf16(af[mi], bfv[ni], acc[mi][ni], 0, 0, 0);
    __syncthreads();
  }

  #pragma unroll
  for (int mi = 0; mi < 2; mi++) {
    #pragma unroll
    for (int ni = 0; ni < 4; ni++) {
      const int row0 = bm * 64 + wm * 32 + mi * 16 + lk * 4;
      const int col  = bn * 128 + wn * 64 + ni * 16 + lr;
      const float bvc = bv[col], il = iLam[col];
      #pragma unroll
      for (int r = 0; r < 4; r++)
        outF[(size_t)(row0 + r) * 256 + col] = (acc[mi][ni][r] + bvc) * il;
    }
  }
}

// ---------------------------------------------------------------------------
// final GEMM: 128x128 tile, K=896; grid 320 XCD-swizzled; dx / y split by col
// ---------------------------------------------------------------------------
__global__ __launch_bounds__(256) void gemm_f(
    const u16* __restrict__ A, const u16* __restrict__ B,
    float* __restrict__ dxOut, float* __restrict__ yOut)
{
  __shared__ __align__(16) u16 As[128 * 32];
  __shared__ __align__(16) u16 Bs[128 * 32];
  const int bid = blockIdx.x;
  const int wg = (bid & 7) * 40 + (bid >> 3);
  const int bm = wg / 5, bn = wg - bm * 5;
  const int tid = threadIdx.x;
  const int l = tid & 63, w = tid >> 6;
  const size_t rowb = 896 * 2;
  const char* Ab = (const char*)A + (size_t)bm * 128 * rowb;
  const char* Bb = (const char*)B + (size_t)bn * 128 * rowb;
  const int o1 = tid * 16, o2 = o1 + 4096;
  const int r1 = o1 >> 6, r2 = o2 >> 6;
  const int c1 = (((o1 >> 4) ^ r1) & 3) << 4;
  const int c2 = (((o2 >> 4) ^ r2) & 3) << 4;
  char* AsB = (char*)As; char* BsB = (char*)Bs;
  const int wm = w >> 1, wn = w & 1;
  const int lr = l & 15, lk = l >> 4;
  const int slot = ((lk ^ lr) & 3) << 4;

  f32x4 acc[4][4];
  const f32x4 zz = {0.f, 0.f, 0.f, 0.f};
  #pragma unroll
  for (int i = 0; i < 4; i++)
    #pragma unroll
    for (int j = 0; j < 4; j++) acc[i][j] = zz;

  for (int k0 = 0; k0 < 896; k0 += 32) {
    gl16(Ab + (size_t)r1 * rowb + k0 * 2 + c1, AsB + o1);
    gl16(Ab + (size_t)r2 * rowb + k0 * 2 + c2, AsB + o2);
    gl16(Bb + (size_t)r1 * rowb + k0 * 2 + c1, BsB + o1);
    gl16(Bb + (size_t)r2 * rowb + k0 * 2 + c2, BsB + o2);
    __syncthreads();
    bf16x8 af[4], bfv[4];
    #pragma unroll
    for (int mi = 0; mi < 4; mi++)
      af[mi] = *(const bf16x8*)(AsB + (wm * 64 + mi * 16 + lr) * 64 + slot);
    #pragma unroll
    for (int ni = 0; ni < 4; ni++)
      bfv[ni] = *(const bf16x8*)(BsB + (wn * 64 + ni * 16 + lr) * 64 + slot);
    #pragma unroll
    for (int mi = 0; mi < 4; mi++)
      #pragma unroll
      for (int ni = 0; ni < 4; ni++)
        acc[mi][ni] = __builtin_amdgcn_mfma_f32_16x16x32_bf16(af[mi], bfv[ni], acc[mi][ni], 0, 0, 0);
    __syncthreads();
  }

  #pragma unroll
  for (int mi = 0; mi < 4; mi++) {
    #pragma unroll
    for (int ni = 0; ni < 4; ni++) {
      const int row0 = bm * 128 + wm * 64 + mi * 16 + lk * 4;
      const int col  = bn * 128 + wn * 64 + ni * 16 + lr;
      #pragma unroll
      for (int r = 0; r < 4; r++) {
        float v = acc[mi][ni][r];
        if (col < 512) dxOut[(size_t)(row0 + r) * 512 + col] = v;
        else           yOut[(size_t)(row0 + r) * 128 + (col - 512)] = v;
      }
    }
  }
}

// ---------------------------------------------------------------------------
// L3 (128 thr): blocks 0..255 = tanh recurrence (32 rows each);
//               blocks 256..319 = Y1 = 2Y0 - Y0@T0 via gemm64h_body<4>
// ---------------------------------------------------------------------------
__global__ __launch_bounds__(128) void k_solve_a(
    const float* __restrict__ base2, const u16* __restrict__ Ddg2,
    const float* __restrict__ Dt16, u16* __restrict__ P, GemmArgs ga)
{
  __shared__ __align__(16) char DdL[2][16384];
  __shared__ __align__(16) float DtL[4096];
  __shared__ __align__(16) float tb[2][16][40];

  if (blockIdx.x >= 256) {
    int q = blockIdx.x - 256;
    gemm64h_body<4>(ga, q >> 3, q & 7, (u16*)&DdL[0][0], (u16*)&DdL[0][4096]);
    return;
  }

  const int tid = threadIdx.x, l = tid & 63, w = tid >> 6;
  const int r = l & 15, g = l >> 4;
  const int row = blockIdx.x * 32 + w * 16 + r;

  const char* DtG = (const char*)Dt16;
  #pragma unroll
  for (int i = 0; i < 8; i++)
    gl16(DtG + i * 2048 + tid * 16, (char*)DtL + i * 2048 + tid * 16);
  const char* DgG = (const char*)Ddg2;
  #pragma unroll
  for (int i = 0; i < 8; i++)
    gl16(DgG + i * 2048 + tid * 16, DdL[0] + i * 2048 + tid * 16);

  f32x4 st[16];
  const float* bp = base2 + (size_t)row * 256 + g * 4;
  #pragma unroll
  for (int t = 0; t < 16; t++) st[t] = *(const f32x4*)(bp + t * 16);

  u32x4 pkA[8];
  float* tbr = &tb[w][r][0];
  __syncthreads();

  #pragma unroll
  for (int sb = 0; sb < 8; sb++) {
    if (sb < 7) {
      #pragma unroll
      for (int i = 0; i < 8; i++)
        gl16(DgG + (sb + 1) * 16384 + i * 2048 + tid * 16,
             DdL[(sb + 1) & 1] + i * 2048 + tid * 16);
    }
    float ws[8];
    #pragma unroll
    for (int i = 0; i < 8; i++) ws[i] = 0.f;
    f32x4 vv[4];

    // ---- lo 16-tile
    *(f32x4*)(tbr + g * 4) = st[2 * sb];
    vv[0] = *(const f32x4*)(tbr);      vv[1] = *(const f32x4*)(tbr + 4);
    vv[2] = *(const f32x4*)(tbr + 8);  vv[3] = *(const f32x4*)(tbr + 12);
    {
      const float* dt = DtL + (2 * sb) * 256;
      #pragma unroll
      for (int k2 = 0; k2 < 16; k2++) {
        float v = vv[k2 >> 2][k2 & 3];
        float ex = __expf(2.f * v);
        float wv = 1.f - 2.f * __fdividef(1.f, ex + 1.f);
        if (g == (k2 >> 3)) ws[k2 & 7] = wv;
        #pragma unroll
        for (int j = k2 >> 2; j < 4; j++)
          vv[j] += wv * *(const f32x4*)(dt + k2 * 16 + j * 4);
      }
    }
    {
      u32x4 pk;
      pk.x = (u32)f2b(ws[0]) | ((u32)f2b(ws[1]) << 16);
      pk.y = (u32)f2b(ws[2]) | ((u32)f2b(ws[3]) << 16);
      pk.z = (u32)f2b(ws[4]) | ((u32)f2b(ws[5]) << 16);
      pk.w = (u32)f2b(ws[6]) | ((u32)f2b(ws[7]) << 16);
      union { u32x4 uu; bf16x8 bb; } cv; cv.uu = pk;
      bf16x8 Af = *(const bf16x8*)(DdL[sb & 1] + (2 * sb + 1) * 1024 + l * 16);
      st[2 * sb + 1] = __builtin_amdgcn_mfma_f32_16x16x32_bf16(Af, cv.bb, st[2 * sb + 1], 0, 0, 0);
    }
    // ---- hi 16-tile
    *(f32x4*)(tbr + g * 4) = st[2 * sb + 1];
    vv[0] = *(const f32x4*)(tbr);      vv[1] = *(const f32x4*)(tbr + 4);
    vv[2] = *(const f32x4*)(tbr + 8);  vv[3] = *(const f32x4*)(tbr + 12);
    {
      const float* dt = DtL + (2 * sb + 1) * 256;
      #pragma unroll
      for (int k2 = 0; k2 < 16; k2++) {
        float v = vv[k2 >> 2][k2 & 3];
        float ex = __expf(2.f * v);
        float wv = 1.f - 2.f * __fdividef(1.f, ex + 1.f);
        if (g == 2 + (k2 >> 3)) ws[k2 & 7] = wv;
        #pragma unroll
        for (int j = k2 >> 2; j < 4; j++)
          vv[j] += wv * *(const f32x4*)(dt + k2 * 16 + j * 4);
      }
    }
    {
      u32x4 pk;
      pk.x = (u32)f2b(ws[0]) | ((u32)f2b(ws[1]) << 16);
      pk.y = (u32)f2b(ws[2]) | ((u32)f2b(ws[3]) << 16);
      pk.z = (u32)f2b(ws[4]) | ((u32)f2b(ws[5]) << 16);
      pk.w = (u32)f2b(ws[6]) | ((u32)f2b(ws[7]) << 16);
      pkA[sb] = pk;
      union { u32x4 uu; bf16x8 bb; } cv; cv.uu = pk;
      #pragma unroll
      for (int t = 0; t < 16; t++) {
        if (t >= 2 * sb + 2) {
          bf16x8 Af = *(const bf16x8*)(DdL[sb & 1] + t * 1024 + l * 16);
          st[t] = __builtin_amdgcn_mfma_f32_16x16x32_bf16(Af, cv.bb, st[t], 0, 0, 0);
        }
      }
    }
    __syncthreads();
  }

  u16* Pr = P + (size_t)row * 896 + 640;
  #pragma unroll
  for (int sb = 0; sb < 8; sb++)
    *(u32x4*)(Pr + sb * 32 + g * 8) = pkA[sb];
}

// ---------------------------------------------------------------------------
extern "C" void kernel_launch(void* const* d_in, const int* in_sizes, int n_in,
                              void* d_out, int out_size, void* d_ws, size_t ws_size,
                              hipStream_t stream)
{
  const float* x   = (const float*)d_in[0];
  const float* u   = (const float*)d_in[1];
  const float* C1  = (const float*)d_in[2];
  const float* D11 = (const float*)d_in[3];
  const float* D12 = (const float*)d_in[4];
  const float* Lam = (const float*)d_in[5];
  const float* bv  = (const float*)d_in[6];
  const float* E   = (const float*)d_in[7];
  const float* F   = (const float*)d_in[8];
  const float* B1  = (const float*)d_in[9];
  const float* B2  = (const float*)d_in[10];
  const float* C2  = (const float*)d_in[11];
  const float* D21 = (const float*)d_in[12];

  char* ws = (char*)d_ws;
  u16*   P      = (u16*)(ws);                 // 14,680,064
  u16*   Qt     = (u16*)(ws + 14680064);      //  1,146,880
  u16*   Rt     = (u16*)(ws + 15826944);      //    327,680
  float* base2  = (float*)(ws + 16285696);    //  8,388,608
  u16*   Ddg2   = (u16*)(ws + 24674304);      //    131,072
  float* Dt16   = (float*)(ws + 24805376);    //     16,384
  u16*   Ebf    = (u16*)(ws + 24838144);      //    524,288
  u16*   Y0     = (u16*)(ws + 25362432);
  u16*   Z0     = (u16*)(ws + 25886720);
  u16*   T0T    = (u16*)(ws + 26411008);
  u16*   Y1     = (u16*)(ws + 26935296);
  u16*   McatT  = (u16*)(ws + 27459584);      //    917,504
  float* invLam = (float*)(ws + 28377088);

  float* dxOut = (float*)d_out;
  float* yOut  = dxOut + (size_t)8192 * 512;

  k_prepc<<<8209, 256, 0, stream>>>(x, u, C1, D11, D12, Lam, E, F, B1, B2, C2, D21,
                                    Ebf, Y0, Z0, McatT, Qt, Rt, invLam, Ddg2, Dt16, P);

  GemmArgs a{}; a.A = Ebf; a.B = Z0; a.K = 512; a.lda = 512; a.ldb = 512; a.outBT = T0T;
  gemm_b2<<<320, 256, 0, stream>>>(P, Rt, base2, bv, invLam, a);     // base2 + T0T

  GemmArgs b{}; b.A = Y0; b.B = T0T; b.K = 512; b.lda = 512; b.ldb = 512;
  b.outB = Y1; b.ldB = 512; b.Yprev = Y0;
  k_solve_a<<<320, 128, 0, stream>>>(base2, Ddg2, Dt16, P, b);       // w + Y1

  GemmArgs qq{}; qq.A = Y1; qq.B = McatT; qq.K = 512; qq.lda = 512; qq.ldb = 512;
  qq.outB = Qt; qq.ldB = 896;
  gemm64<2><<<dim3(14, 8), 256, 0, stream>>>(qq);                    // Qt[0:512]

  gemm_f<<<320, 256, 0, stream>>>(P, Qt, dxOut, yOut);               // [dx | y]
  (void)in_sizes; (void)n_in; (void)out_size; (void)ws_size;
}